// Round 1
// baseline (908.750 us; speedup 1.0000x reference)
//
#include <hip/hip_runtime.h>
#include <hip/hip_bf16.h>

#define NB 4
#define SEQ 1024
#define CH 1024
#define NH 16
#define DH 64

// ---------------------------------------------------------------------------
// Generic fp32 GEMM: C[M,N] = A[M,K] @ B[K,N] + bias[N]
// 64x64 tile, BK=16, 256 threads, 4x4 micro-tile, float4 LDS reads.
// ---------------------------------------------------------------------------
__global__ __launch_bounds__(256) void gemm_bias_f32(
    const float* __restrict__ A, const float* __restrict__ Bm,
    const float* __restrict__ bias, float* __restrict__ Cout,
    int M, int Nn, int K)
{
    __shared__ float As[16][68];   // [k][m] transposed
    __shared__ float Bs[16][68];   // [k][n]
    const int t = threadIdx.x;
    const int bm0 = blockIdx.y * 64;
    const int bn0 = blockIdx.x * 64;
    const int tr = t >> 4, tc = t & 15;

    float acc[4][4];
#pragma unroll
    for (int i = 0; i < 4; i++)
#pragma unroll
        for (int j = 0; j < 4; j++) acc[i][j] = 0.f;

    for (int k0 = 0; k0 < K; k0 += 16) {
        {
            int m = t >> 2, kq = (t & 3) * 4;
            float4 v = *(const float4*)(A + (size_t)(bm0 + m) * K + k0 + kq);
            As[kq + 0][m] = v.x; As[kq + 1][m] = v.y;
            As[kq + 2][m] = v.z; As[kq + 3][m] = v.w;
        }
        {
            int kk = t >> 4, n4 = (t & 15) * 4;
            float4 v = *(const float4*)(Bm + (size_t)(k0 + kk) * Nn + bn0 + n4);
            *(float4*)&Bs[kk][n4] = v;
        }
        __syncthreads();
#pragma unroll
        for (int kk = 0; kk < 16; kk++) {
            float4 a = *(const float4*)&As[kk][tr * 4];
            float4 b = *(const float4*)&Bs[kk][tc * 4];
            float av[4] = {a.x, a.y, a.z, a.w};
            float bv[4] = {b.x, b.y, b.z, b.w};
#pragma unroll
            for (int i = 0; i < 4; i++)
#pragma unroll
                for (int j = 0; j < 4; j++)
                    acc[i][j] = fmaf(av[i], bv[j], acc[i][j]);
        }
        __syncthreads();
    }
    float4 bb = *(const float4*)(bias + bn0 + tc * 4);
#pragma unroll
    for (int i = 0; i < 4; i++) {
        float4 o;
        o.x = acc[i][0] + bb.x; o.y = acc[i][1] + bb.y;
        o.z = acc[i][2] + bb.z; o.w = acc[i][3] + bb.w;
        *(float4*)(Cout + (size_t)(bm0 + tr * 4 + i) * Nn + bn0 + tc * 4) = o;
    }
}

// ---------------------------------------------------------------------------
// scores[b,h,n,m] = (q[b,n,h,:] . k[b,m,h,:]) / 8   (K=64, one shot)
// q,k layout: [B*SEQ, CH] with head h at column h*64.
// ---------------------------------------------------------------------------
__global__ __launch_bounds__(256) void scores_f32(
    const float* __restrict__ q, const float* __restrict__ k,
    float* __restrict__ attn)
{
    __shared__ float Qs[64][68];   // [dh][row]
    __shared__ float Ks[64][68];   // [dh][col]
    const int t = threadIdx.x;
    const int bh = blockIdx.z;
    const int b = bh >> 4, h = bh & 15;
    const int n0 = blockIdx.y * 64, m0 = blockIdx.x * 64;
    const float* qb = q + (size_t)b * SEQ * CH + h * DH;
    const float* kb = k + (size_t)b * SEQ * CH + h * DH;

    const int r = t >> 2, d4 = (t & 3) * 4;
#pragma unroll
    for (int c = 0; c < 4; c++) {
        int dh0 = d4 + 16 * c;
        float4 v = *(const float4*)(qb + (size_t)(n0 + r) * CH + dh0);
        Qs[dh0 + 0][r] = v.x * 0.125f; Qs[dh0 + 1][r] = v.y * 0.125f;
        Qs[dh0 + 2][r] = v.z * 0.125f; Qs[dh0 + 3][r] = v.w * 0.125f;
        float4 w = *(const float4*)(kb + (size_t)(m0 + r) * CH + dh0);
        Ks[dh0 + 0][r] = w.x; Ks[dh0 + 1][r] = w.y;
        Ks[dh0 + 2][r] = w.z; Ks[dh0 + 3][r] = w.w;
    }
    __syncthreads();

    const int tr = t >> 4, tc = t & 15;
    float acc[4][4];
#pragma unroll
    for (int i = 0; i < 4; i++)
#pragma unroll
        for (int j = 0; j < 4; j++) acc[i][j] = 0.f;

#pragma unroll 8
    for (int kk = 0; kk < 64; kk++) {
        float4 a = *(const float4*)&Qs[kk][tr * 4];
        float4 b2 = *(const float4*)&Ks[kk][tc * 4];
        float av[4] = {a.x, a.y, a.z, a.w};
        float bv[4] = {b2.x, b2.y, b2.z, b2.w};
#pragma unroll
        for (int i = 0; i < 4; i++)
#pragma unroll
            for (int j = 0; j < 4; j++)
                acc[i][j] = fmaf(av[i], bv[j], acc[i][j]);
    }
    float* out = attn + (size_t)bh * SEQ * SEQ;
#pragma unroll
    for (int i = 0; i < 4; i++) {
        float4 o;
        o.x = acc[i][0]; o.y = acc[i][1]; o.z = acc[i][2]; o.w = acc[i][3];
        *(float4*)(out + (size_t)(n0 + tr * 4 + i) * SEQ + m0 + tc * 4) = o;
    }
}

// ---------------------------------------------------------------------------
// entmax-bisect (alpha=1.5) per row of 1024, in place.  One wave per row,
// row resident in 16 VGPRs/lane, 30 bisection iterations (fp32-converged).
// ---------------------------------------------------------------------------
__global__ __launch_bounds__(256) void entmax_rows(float* __restrict__ S)
{
    const int wid = threadIdx.x >> 6;
    const int lane = threadIdx.x & 63;
    const size_t row = (size_t)blockIdx.x * 4 + wid;
    float* base = S + row * SEQ;

    float xa[16];
#pragma unroll
    for (int c = 0; c < 4; c++) {
        float4 v = *(const float4*)(base + c * 256 + lane * 4);
        xa[c * 4 + 0] = v.x * 0.5f; xa[c * 4 + 1] = v.y * 0.5f;
        xa[c * 4 + 2] = v.z * 0.5f; xa[c * 4 + 3] = v.w * 0.5f;
    }
    float m = xa[0];
#pragma unroll
    for (int i = 1; i < 16; i++) m = fmaxf(m, xa[i]);
#pragma unroll
    for (int off = 1; off < 64; off <<= 1) m = fmaxf(m, __shfl_xor(m, off));

    float tau_lo = m - 1.0f;
    float dm = 0.96875f;            // tau_hi - tau_lo = 1 - (1/1024)^0.5
    float s = 0.f;
#pragma unroll
    for (int i = 0; i < 16; i++) {
        float d = fmaxf(xa[i] - tau_lo, 0.f);
        s = fmaf(d, d, s);
    }
#pragma unroll
    for (int off = 1; off < 64; off <<= 1) s += __shfl_xor(s, off);
    const float f_lo = s - 1.0f;

    float tau_m = tau_lo;
    for (int it = 0; it < 30; ++it) {
        dm *= 0.5f;
        tau_m = tau_lo + dm;
        float sm = 0.f;
#pragma unroll
        for (int i = 0; i < 16; i++) {
            float d = fmaxf(xa[i] - tau_m, 0.f);
            sm = fmaf(d, d, sm);
        }
#pragma unroll
        for (int off = 1; off < 64; off <<= 1) sm += __shfl_xor(sm, off);
        float f_m = sm - 1.0f;
        if (f_m * f_lo >= 0.f) tau_lo = tau_m;
    }

    float p[16];
    float S2 = 0.f;
#pragma unroll
    for (int i = 0; i < 16; i++) {
        float d = fmaxf(xa[i] - tau_m, 0.f);
        p[i] = d * d;
        S2 += p[i];
    }
#pragma unroll
    for (int off = 1; off < 64; off <<= 1) S2 += __shfl_xor(S2, off);
    const float inv = 1.0f / S2;
#pragma unroll
    for (int c = 0; c < 4; c++) {
        float4 v;
        v.x = p[c * 4 + 0] * inv; v.y = p[c * 4 + 1] * inv;
        v.z = p[c * 4 + 2] * inv; v.w = p[c * 4 + 3] * inv;
        *(float4*)(base + c * 256 + lane * 4) = v;
    }
}

// ---------------------------------------------------------------------------
// o[b,n,h,:] = sum_m attn[b,h,n,m] * v[b,m,h,:]     (N=64 per head)
// ---------------------------------------------------------------------------
__global__ __launch_bounds__(256) void pv_f32(
    const float* __restrict__ attn, const float* __restrict__ v,
    float* __restrict__ o)
{
    __shared__ float As[16][68];   // [k][m-row]
    __shared__ float Vs[16][68];   // [k][dh]
    const int t = threadIdx.x;
    const int bh = blockIdx.y;
    const int b = bh >> 4, h = bh & 15;
    const int n0 = blockIdx.x * 64;
    const float* ab = attn + (size_t)bh * SEQ * SEQ;
    const float* vb = v + (size_t)b * SEQ * CH + h * DH;
    const int tr = t >> 4, tc = t & 15;

    float acc[4][4];
#pragma unroll
    for (int i = 0; i < 4; i++)
#pragma unroll
        for (int j = 0; j < 4; j++) acc[i][j] = 0.f;

    for (int k0 = 0; k0 < SEQ; k0 += 16) {
        {
            int m = t >> 2, kq = (t & 3) * 4;
            float4 a = *(const float4*)(ab + (size_t)(n0 + m) * SEQ + k0 + kq);
            As[kq + 0][m] = a.x; As[kq + 1][m] = a.y;
            As[kq + 2][m] = a.z; As[kq + 3][m] = a.w;
        }
        {
            int kk = t >> 4, d4 = (t & 15) * 4;
            float4 w = *(const float4*)(vb + (size_t)(k0 + kk) * CH + d4);
            *(float4*)&Vs[kk][d4] = w;
        }
        __syncthreads();
#pragma unroll
        for (int kk = 0; kk < 16; kk++) {
            float4 a = *(const float4*)&As[kk][tr * 4];
            float4 b2 = *(const float4*)&Vs[kk][tc * 4];
            float av[4] = {a.x, a.y, a.z, a.w};
            float bv[4] = {b2.x, b2.y, b2.z, b2.w};
#pragma unroll
            for (int i = 0; i < 4; i++)
#pragma unroll
                for (int j = 0; j < 4; j++)
                    acc[i][j] = fmaf(av[i], bv[j], acc[i][j]);
        }
        __syncthreads();
    }
#pragma unroll
    for (int i = 0; i < 4; i++) {
        float4 ov;
        ov.x = acc[i][0]; ov.y = acc[i][1]; ov.z = acc[i][2]; ov.w = acc[i][3];
        *(float4*)(o + (size_t)(b * SEQ + n0 + tr * 4 + i) * CH + h * DH + tc * 4) = ov;
    }
}

// ---------------------------------------------------------------------------
extern "C" void kernel_launch(void* const* d_in, const int* in_sizes, int n_in,
                              void* d_out, int out_size, void* d_ws, size_t ws_size,
                              hipStream_t stream)
{
    const float* x  = (const float*)d_in[0];
    const float* Wq = (const float*)d_in[1];
    const float* bq = (const float*)d_in[2];
    const float* Wk = (const float*)d_in[3];
    const float* bk = (const float*)d_in[4];
    const float* Wv = (const float*)d_in[5];
    const float* bv = (const float*)d_in[6];
    const float* Wo = (const float*)d_in[7];
    const float* bo = (const float*)d_in[8];

    float* out0 = (float*)d_out;                       // [B, SEQ, CH]
    float* attn = out0 + (size_t)NB * SEQ * CH;        // [B, H, SEQ, SEQ]

    const size_t tsz = (size_t)NB * SEQ * CH;          // 4.19M floats
    float* q = (float*)d_ws;
    float* k = q + tsz;
    float* v = k + tsz;
    float* o = v + tsz;

    const int M = NB * SEQ;   // 4096

    // Q/K/V projections
    gemm_bias_f32<<<dim3(CH / 64, M / 64), 256, 0, stream>>>(x, Wq, bq, q, M, CH, CH);
    gemm_bias_f32<<<dim3(CH / 64, M / 64), 256, 0, stream>>>(x, Wk, bk, k, M, CH, CH);
    gemm_bias_f32<<<dim3(CH / 64, M / 64), 256, 0, stream>>>(x, Wv, bv, v, M, CH, CH);

    // scores -> attn region (scratch), then entmax in place
    scores_f32<<<dim3(SEQ / 64, SEQ / 64, NB * NH), 256, 0, stream>>>(q, k, attn);
    entmax_rows<<<(NB * NH * SEQ) / 4, 256, 0, stream>>>(attn);

    // PV and output projection
    pv_f32<<<dim3(SEQ / 64, NB * NH), 256, 0, stream>>>(attn, v, o);
    gemm_bias_f32<<<dim3(CH / 64, M / 64), 256, 0, stream>>>(o, Wo, bo, out0, M, CH, CH);
}

// Round 2
// 659.897 us; speedup vs baseline: 1.3771x; 1.3771x over previous
//
#include <hip/hip_runtime.h>
#include <hip/hip_bf16.h>
#include <stdint.h>

#define NBAT 4
#define SEQ 1024
#define CH 1024
#define NH 16
#define DH 64
#define MTOT (NBAT*SEQ)   // 4096

typedef __attribute__((ext_vector_type(8))) short bf16x8;
typedef __attribute__((ext_vector_type(4))) float f32x4;
typedef unsigned short u16;

__device__ __forceinline__ void g2l16(void* lds, const void* g) {
  __builtin_amdgcn_global_load_lds(
      (const __attribute__((address_space(1))) uint32_t*)g,
      (__attribute__((address_space(3))) uint32_t*)lds, 16, 0, 0);
}

__device__ __forceinline__ u16 f2bf(float f) {   // RNE float->bf16
  union { float f; uint32_t u; } v; v.f = f;
  uint32_t lsb = (v.u >> 16) & 1u;
  v.u += 0x7fffu + lsb;
  return (u16)(v.u >> 16);
}

// ---------------------------------------------------------------------------
// x fp32 -> bf16 (4M elems)
// ---------------------------------------------------------------------------
__global__ __launch_bounds__(256) void cvt_x(const float* __restrict__ x,
                                             u16* __restrict__ xb) {
  int i = blockIdx.x * 256 + threadIdx.x;
  float4 v = ((const float4*)x)[i];
  ushort4 o;
  o.x = f2bf(v.x); o.y = f2bf(v.y); o.z = f2bf(v.z); o.w = f2bf(v.w);
  ((ushort4*)xb)[i] = o;
}

// ---------------------------------------------------------------------------
// W fp32 [1024][1024] -> Wt bf16 [n][k] (transposed), 64x64 tiles
// ---------------------------------------------------------------------------
__global__ __launch_bounds__(256) void wt_bf16(const float* __restrict__ W,
                                               u16* __restrict__ Wt) {
  __shared__ u16 tile[64][65];
  const int bi = blockIdx.x;      // n-tile
  const int bj = blockIdx.y;      // k-tile
  const int t = threadIdx.x;
  const int c4 = (t & 15) * 4, rr = t >> 4;
#pragma unroll
  for (int p = 0; p < 4; p++) {
    int r = p * 16 + rr;          // k within tile
    float4 v = *(const float4*)(W + (size_t)(bj * 64 + r) * CH + bi * 64 + c4);
    tile[r][c4 + 0] = f2bf(v.x); tile[r][c4 + 1] = f2bf(v.y);
    tile[r][c4 + 2] = f2bf(v.z); tile[r][c4 + 3] = f2bf(v.w);
  }
  __syncthreads();
  const int n = t >> 2, ks = (t & 3) * 16;
  u16 tmp[16];
#pragma unroll
  for (int i = 0; i < 16; i++) tmp[i] = tile[ks + i][n];
#pragma unroll
  for (int s = 0; s < 4; s++) {
    ushort4 o; o.x = tmp[4*s]; o.y = tmp[4*s+1]; o.z = tmp[4*s+2]; o.w = tmp[4*s+3];
    *(ushort4*)(Wt + (size_t)(bi * 64 + n) * CH + bj * 64 + ks + 4 * s) = o;
  }
}

// ---------------------------------------------------------------------------
// bf16 MFMA GEMM: C[4096][1024] = A[4096][1024] @ Bt^T + bias
// Bt is pre-transposed [n][k].  MODE 0: bf16 out [M][N]; MODE 1: bf16 out
// transposed [N][M] (v_t); MODE 2: fp32 out [M][N].
// 128x128 tile, BK=32, 256 thr = 4 waves (2x2), wave 64x64 = 4x4 frags.
// ---------------------------------------------------------------------------
template<int MODE>
__global__ __launch_bounds__(256) void gemm128(
    const u16* __restrict__ A, const u16* __restrict__ Bt,
    const float* __restrict__ bias, void* __restrict__ outp)
{
  __shared__ u16 As[128 * 32];
  __shared__ u16 Bs[128 * 32];
  const int t = threadIdx.x;
  const int bn0 = blockIdx.x * 128;
  const int bm0 = blockIdx.y * 128;
  const int wid = t >> 6, lane = t & 63;
  const int wr = wid >> 1, wc = wid & 1;
  const int cl = lane & 15, g = lane >> 4;

  f32x4 acc[4][4] = {};
  const u16* ga = A  + (size_t)(bm0 + (t >> 2)) * CH + (t & 3) * 8;
  const u16* gb = Bt + (size_t)(bn0 + (t >> 2)) * CH + (t & 3) * 8;

  for (int k0 = 0; k0 < CH; k0 += 32) {
    g2l16(As + t * 8,        ga + k0);
    g2l16(As + 2048 + t * 8, ga + (size_t)64 * CH + k0);
    g2l16(Bs + t * 8,        gb + k0);
    g2l16(Bs + 2048 + t * 8, gb + (size_t)64 * CH + k0);
    __syncthreads();
    bf16x8 af[4], bfr[4];
#pragma unroll
    for (int f = 0; f < 4; f++) {
      af[f]  = *(const bf16x8*)(As + (wr * 64 + f * 16 + cl) * 32 + g * 8);
      bfr[f] = *(const bf16x8*)(Bs + (wc * 64 + f * 16 + cl) * 32 + g * 8);
    }
#pragma unroll
    for (int i = 0; i < 4; i++)
#pragma unroll
      for (int j = 0; j < 4; j++)
        acc[i][j] = __builtin_amdgcn_mfma_f32_16x16x32_bf16(af[i], bfr[j], acc[i][j], 0, 0, 0);
    __syncthreads();
  }

#pragma unroll
  for (int i = 0; i < 4; i++)
#pragma unroll
    for (int j = 0; j < 4; j++) {
      const int row0 = bm0 + wr * 64 + i * 16 + g * 4;
      const int col  = bn0 + wc * 64 + j * 16 + cl;
      const float bb = bias[col];
      f32x4 v = acc[i][j];
      if (MODE == 0) {
        u16* o = (u16*)outp;
#pragma unroll
        for (int q = 0; q < 4; q++) o[(size_t)(row0 + q) * CH + col] = f2bf(v[q] + bb);
      } else if (MODE == 1) {
        u16* o = (u16*)outp;
        ushort4 pk;
        pk.x = f2bf(v[0] + bb); pk.y = f2bf(v[1] + bb);
        pk.z = f2bf(v[2] + bb); pk.w = f2bf(v[3] + bb);
        *(ushort4*)(o + (size_t)col * MTOT + row0) = pk;
      } else {
        float* o = (float*)outp;
#pragma unroll
        for (int q = 0; q < 4; q++) o[(size_t)(row0 + q) * CH + col] = v[q] + bb;
      }
    }
}

// ---------------------------------------------------------------------------
// Fused scores -> entmax(1.5, bisect) -> PV.
// Block: 512 thr (8 waves), one (b,h) x 32 Q-rows. Scores via MFMA in 128-col
// chunks bounced through LDS into per-lane regs (lane holds cols {l, l+64} of
// each chunk); wave w owns rows 4w..4w+3. 26 bisection iters in registers.
// p written fp32 to attn (d_out) and kept packed bf16 for PV MFMA.
// ---------------------------------------------------------------------------
__global__ __launch_bounds__(512, 4) void fused_attn(
    const u16* __restrict__ q, const u16* __restrict__ k,
    const u16* __restrict__ vt, float* __restrict__ attn,
    u16* __restrict__ o)
{
  __shared__ u16  qt[32 * 64];      // 4 KB
  __shared__ u16  kv[128 * 64];     // 16 KB (K chunks, then V chunks)
  __shared__ float scb[32 * 129];   // 16.1 KB score bounce
  __shared__ u16  pcb[32 * 128];    // 8 KB P chunk (bf16)

  const int t = threadIdx.x;
  const int wid = t >> 6, lane = t & 63;
  const int cl = lane & 15, g = lane >> 4;
  const int n0 = blockIdx.x * 32;
  const int bh = blockIdx.y;
  const int b = bh >> 4, h = bh & 15;
  const int r0 = wid * 4;

  const u16* qb = q  + ((size_t)(b * SEQ + n0) * CH + h * DH);
  const u16* kb = k  + ((size_t)(b * SEQ) * CH + h * DH);
  const u16* vb = vt + ((size_t)(h * DH) * MTOT + b * SEQ);

  if (t < 256)
    g2l16(qt + t * 8, qb + (size_t)(t >> 3) * CH + (t & 7) * 8);

  const int swr = wid >> 2, swc = wid & 3;   // scores: rows 16*swr, cols 32*swc
  float xa[4][16];

#pragma unroll
  for (int mc = 0; mc < 8; ++mc) {
    const u16* kc = kb + (size_t)(mc * 128) * CH;
    g2l16(kv + t * 8,        kc + (size_t)(t >> 3) * CH + (t & 7) * 8);
    g2l16(kv + 4096 + t * 8, kc + (size_t)((t >> 3) + 64) * CH + (t & 7) * 8);
    __syncthreads();                                   // B1: kv/qt ready
    f32x4 sa[2] = {};
#pragma unroll
    for (int ks = 0; ks < 2; ks++) {
      bf16x8 aq = *(const bf16x8*)(qt + (swr * 16 + cl) * 64 + ks * 32 + g * 8);
#pragma unroll
      for (int fj = 0; fj < 2; fj++) {
        bf16x8 bk_ = *(const bf16x8*)(kv + (swc * 32 + fj * 16 + cl) * 64 + ks * 32 + g * 8);
        sa[fj] = __builtin_amdgcn_mfma_f32_16x16x32_bf16(aq, bk_, sa[fj], 0, 0, 0);
      }
    }
#pragma unroll
    for (int fj = 0; fj < 2; fj++)
#pragma unroll
      for (int qq = 0; qq < 4; qq++)
        scb[(swr * 16 + g * 4 + qq) * 129 + swc * 32 + fj * 16 + cl] = sa[fj][qq] * 0.125f;
    __syncthreads();                                   // B2: scb ready
#pragma unroll
    for (int r = 0; r < 4; r++) {
      xa[r][2 * mc]     = scb[(r0 + r) * 129 + lane] * 0.5f;
      xa[r][2 * mc + 1] = scb[(r0 + r) * 129 + 64 + lane] * 0.5f;
    }
    __syncthreads();                                   // Z: reads done
  }

  // ---- entmax bisection (alpha=1.5), 4 rows per wave, all in registers ----
  float tlo[4], flo[4], tm[4];
#pragma unroll
  for (int r = 0; r < 4; r++) {
    float m = xa[r][0];
#pragma unroll
    for (int j = 1; j < 16; j++) m = fmaxf(m, xa[r][j]);
#pragma unroll
    for (int off = 1; off < 64; off <<= 1) m = fmaxf(m, __shfl_xor(m, off));
    tlo[r] = m - 1.0f;
    float s = 0.f;
#pragma unroll
    for (int j = 0; j < 16; j++) { float d = fmaxf(xa[r][j] - tlo[r], 0.f); s = fmaf(d, d, s); }
#pragma unroll
    for (int off = 1; off < 64; off <<= 1) s += __shfl_xor(s, off);
    flo[r] = s - 1.0f;
    tm[r] = tlo[r];
  }
  float dm = 0.96875f;   // 1 - (1/1024)^0.5
  for (int it = 0; it < 26; ++it) {
    dm *= 0.5f;
    float s[4];
#pragma unroll
    for (int r = 0; r < 4; r++) {
      tm[r] = tlo[r] + dm;
      float ss = 0.f;
#pragma unroll
      for (int j = 0; j < 16; j++) { float d = fmaxf(xa[r][j] - tm[r], 0.f); ss = fmaf(d, d, ss); }
      s[r] = ss;
    }
#pragma unroll
    for (int off = 1; off < 64; off <<= 1) {
#pragma unroll
      for (int r = 0; r < 4; r++) s[r] += __shfl_xor(s[r], off);
    }
#pragma unroll
    for (int r = 0; r < 4; r++)
      if ((s[r] - 1.0f) * flo[r] >= 0.f) tlo[r] = tm[r];
  }

  // ---- p, normalize, write attn fp32, pack bf16 ----
  uint32_t pbp[4][8];
#pragma unroll
  for (int r = 0; r < 4; r++) {
    float p[16]; float s2 = 0.f;
#pragma unroll
    for (int j = 0; j < 16; j++) { float d = fmaxf(xa[r][j] - tm[r], 0.f); p[j] = d * d; s2 += p[j]; }
#pragma unroll
    for (int off = 1; off < 64; off <<= 1) s2 += __shfl_xor(s2, off);
    const float inv = 1.0f / s2;
    float* ar = attn + (size_t)bh * SEQ * SEQ + (size_t)(n0 + r0 + r) * SEQ;
#pragma unroll
    for (int j = 0; j < 16; j++) { p[j] *= inv; ar[64 * j + lane] = p[j]; }
#pragma unroll
    for (int vc = 0; vc < 8; vc++)
      pbp[r][vc] = (uint32_t)f2bf(p[2 * vc]) | ((uint32_t)f2bf(p[2 * vc + 1]) << 16);
  }

  // ---- PV: out[32][64] = P[32][1024] @ V[1024][64] in 128-row chunks ----
  const int pwr = wid >> 2, pwc = wid & 3;   // rows 16*pwr, dh cols 16*pwc
  f32x4 pv = {};
#pragma unroll
  for (int vc = 0; vc < 8; ++vc) {
    const u16* vcp = vb + vc * 128;
    g2l16(kv + t * 8,        vcp + (size_t)(t >> 4) * MTOT + (t & 15) * 8);
    g2l16(kv + 4096 + t * 8, vcp + (size_t)((t >> 4) + 32) * MTOT + (t & 15) * 8);
#pragma unroll
    for (int r = 0; r < 4; r++) {
      uint32_t u = pbp[r][vc];
      pcb[(r0 + r) * 128 + lane]      = (u16)(u & 0xffffu);
      pcb[(r0 + r) * 128 + 64 + lane] = (u16)(u >> 16);
    }
    __syncthreads();                                   // vbuf + pcb ready
#pragma unroll
    for (int ks = 0; ks < 4; ks++) {
      bf16x8 ap  = *(const bf16x8*)(pcb + (pwr * 16 + cl) * 128 + ks * 32 + g * 8);
      bf16x8 bv_ = *(const bf16x8*)(kv  + (pwc * 16 + cl) * 128 + ks * 32 + g * 8);
      pv = __builtin_amdgcn_mfma_f32_16x16x32_bf16(ap, bv_, pv, 0, 0, 0);
    }
    __syncthreads();                                   // reads done
  }
  u16* ob = o + ((size_t)(b * SEQ + n0 + pwr * 16 + g * 4) * CH + h * DH + pwc * 16 + cl);
#pragma unroll
  for (int qq = 0; qq < 4; qq++)
    ob[(size_t)qq * CH] = f2bf(pv[qq]);
}

// ---------------------------------------------------------------------------
extern "C" void kernel_launch(void* const* d_in, const int* in_sizes, int n_in,
                              void* d_out, int out_size, void* d_ws, size_t ws_size,
                              hipStream_t stream)
{
  const float* x  = (const float*)d_in[0];
  const float* Wq = (const float*)d_in[1];
  const float* bq = (const float*)d_in[2];
  const float* Wk = (const float*)d_in[3];
  const float* bk = (const float*)d_in[4];
  const float* Wv = (const float*)d_in[5];
  const float* bv = (const float*)d_in[6];
  const float* Wo = (const float*)d_in[7];
  const float* bo = (const float*)d_in[8];

  float* out0 = (float*)d_out;                        // [B,SEQ,CH] fp32
  float* attn = out0 + (size_t)NBAT * SEQ * CH;       // [B,H,SEQ,SEQ] fp32

  const size_t T = (size_t)MTOT * CH;                 // 4M elems
  u16* xb  = (u16*)d_ws;
  u16* qw  = xb  + T;
  u16* kw  = qw  + T;
  u16* vtw = kw  + T;
  u16* ow  = vtw + T;
  u16* wtq = ow  + T;
  u16* wtk = wtq + (size_t)CH * CH;
  u16* wtv = wtk + (size_t)CH * CH;
  u16* wto = wtv + (size_t)CH * CH;

  cvt_x<<<T / (4 * 256), 256, 0, stream>>>(x, xb);
  wt_bf16<<<dim3(16, 16), 256, 0, stream>>>(Wq, wtq);
  wt_bf16<<<dim3(16, 16), 256, 0, stream>>>(Wk, wtk);
  wt_bf16<<<dim3(16, 16), 256, 0, stream>>>(Wv, wtv);
  wt_bf16<<<dim3(16, 16), 256, 0, stream>>>(Wo, wto);

  gemm128<0><<<dim3(CH / 128, MTOT / 128), 256, 0, stream>>>(xb, wtq, bq, qw);
  gemm128<0><<<dim3(CH / 128, MTOT / 128), 256, 0, stream>>>(xb, wtk, bk, kw);
  gemm128<1><<<dim3(CH / 128, MTOT / 128), 256, 0, stream>>>(xb, wtv, bv, vtw);

  fused_attn<<<dim3(SEQ / 32, NBAT * NH), 512, 0, stream>>>(qw, kw, vtw, attn, ow);

  gemm128<2><<<dim3(CH / 128, MTOT / 128), 256, 0, stream>>>(ow, wto, bo, out0);
}

// Round 4
// 379.984 us; speedup vs baseline: 2.3916x; 1.7366x over previous
//
#include <hip/hip_runtime.h>
#include <hip/hip_bf16.h>
#include <stdint.h>

#define NBAT 4
#define SEQ 1024
#define CH 1024
#define NH 16
#define DH 64
#define MTOT (NBAT*SEQ)   // 4096

typedef __attribute__((ext_vector_type(8))) short bf16x8;
typedef __attribute__((ext_vector_type(4))) float f32x4;
typedef unsigned short u16;

// Raw barrier is NOT a compiler fence: bracket it so LDS ops can't be
// hoisted above / sunk below it (R2's correctness bug).
#define FENCE() asm volatile("" ::: "memory")
#define BAR() do { FENCE(); __builtin_amdgcn_s_barrier(); FENCE(); } while (0)
#define WAIT_VM2() asm volatile("s_waitcnt vmcnt(2)" ::: "memory")
#define WAIT_VM0() asm volatile("s_waitcnt vmcnt(0)" ::: "memory")
#define WAIT_LGKM0() asm volatile("s_waitcnt lgkmcnt(0)" ::: "memory")

__device__ __forceinline__ void g2l16(void* lds, const void* g) {
  __builtin_amdgcn_global_load_lds(
      (const __attribute__((address_space(1))) uint32_t*)g,
      (__attribute__((address_space(3))) uint32_t*)lds, 16, 0, 0);
}

__device__ __forceinline__ u16 f2bf(float f) {   // RNE float->bf16
  union { float f; uint32_t u; } v; v.f = f;
  uint32_t lsb = (v.u >> 16) & 1u;
  v.u += 0x7fffu + lsb;
  return (u16)(v.u >> 16);
}

// swizzled bf16x8 fragment read from a [rows][64 u16] LDS tile (128 B rows)
__device__ __forceinline__ bf16x8 ldfrag(const u16* base, int row, int koff) {
  return *(const bf16x8*)((const char*)base + row * 128 + (koff ^ ((row & 7) << 4)));
}

// ---------------------------------------------------------------------------
// x fp32 -> bf16 (4M elems)
// ---------------------------------------------------------------------------
__global__ __launch_bounds__(256) void cvt_x(const float* __restrict__ x,
                                             u16* __restrict__ xb) {
  int i = blockIdx.x * 256 + threadIdx.x;
  float4 v = ((const float4*)x)[i];
  ushort4 o;
  o.x = f2bf(v.x); o.y = f2bf(v.y); o.z = f2bf(v.z); o.w = f2bf(v.w);
  ((ushort4*)xb)[i] = o;
}

// ---------------------------------------------------------------------------
// W fp32 [1024][1024] -> Wt bf16 [n][k] (transposed), 64x64 tiles
// ---------------------------------------------------------------------------
__global__ __launch_bounds__(256) void wt_bf16(const float* __restrict__ W,
                                               u16* __restrict__ Wt) {
  __shared__ u16 tile[64][65];
  const int bi = blockIdx.x;      // n-tile
  const int bj = blockIdx.y;      // k-tile
  const int t = threadIdx.x;
  const int c4 = (t & 15) * 4, rr = t >> 4;
#pragma unroll
  for (int p = 0; p < 4; p++) {
    int r = p * 16 + rr;          // k within tile
    float4 v = *(const float4*)(W + (size_t)(bj * 64 + r) * CH + bi * 64 + c4);
    tile[r][c4 + 0] = f2bf(v.x); tile[r][c4 + 1] = f2bf(v.y);
    tile[r][c4 + 2] = f2bf(v.z); tile[r][c4 + 3] = f2bf(v.w);
  }
  __syncthreads();
  const int n = t >> 2, ks = (t & 3) * 16;
  u16 tmp[16];
#pragma unroll
  for (int i = 0; i < 16; i++) tmp[i] = tile[ks + i][n];
#pragma unroll
  for (int s = 0; s < 4; s++) {
    ushort4 o; o.x = tmp[4*s]; o.y = tmp[4*s+1]; o.z = tmp[4*s+2]; o.w = tmp[4*s+3];
    *(ushort4*)(Wt + (size_t)(bi * 64 + n) * CH + bj * 64 + ks + 4 * s) = o;
  }
}

// ---------------------------------------------------------------------------
// bf16 MFMA GEMM: C[4096][1024] = A[4096][1024] @ Bt^T + bias
// MODE 0: bf16 out [M][N]; MODE 1: bf16 out transposed [N][M]; MODE 2: fp32.
// ---------------------------------------------------------------------------
template<int MODE>
__global__ __launch_bounds__(256) void gemm128(
    const u16* __restrict__ A, const u16* __restrict__ Bt,
    const float* __restrict__ bias, void* __restrict__ outp)
{
  __shared__ u16 As[128 * 32];
  __shared__ u16 Bs[128 * 32];
  const int t = threadIdx.x;
  const int bn0 = blockIdx.x * 128;
  const int bm0 = blockIdx.y * 128;
  const int wid = t >> 6, lane = t & 63;
  const int wr = wid >> 1, wc = wid & 1;
  const int cl = lane & 15, g = lane >> 4;

  f32x4 acc[4][4] = {};
  const u16* ga = A  + (size_t)(bm0 + (t >> 2)) * CH + (t & 3) * 8;
  const u16* gb = Bt + (size_t)(bn0 + (t >> 2)) * CH + (t & 3) * 8;

  for (int k0 = 0; k0 < CH; k0 += 32) {
    g2l16(As + t * 8,        ga + k0);
    g2l16(As + 2048 + t * 8, ga + (size_t)64 * CH + k0);
    g2l16(Bs + t * 8,        gb + k0);
    g2l16(Bs + 2048 + t * 8, gb + (size_t)64 * CH + k0);
    __syncthreads();
    bf16x8 af[4], bfr[4];
#pragma unroll
    for (int f = 0; f < 4; f++) {
      af[f]  = *(const bf16x8*)(As + (wr * 64 + f * 16 + cl) * 32 + g * 8);
      bfr[f] = *(const bf16x8*)(Bs + (wc * 64 + f * 16 + cl) * 32 + g * 8);
    }
#pragma unroll
    for (int i = 0; i < 4; i++)
#pragma unroll
      for (int j = 0; j < 4; j++)
        acc[i][j] = __builtin_amdgcn_mfma_f32_16x16x32_bf16(af[i], bfr[j], acc[i][j], 0, 0, 0);
    __syncthreads();
  }

#pragma unroll
  for (int i = 0; i < 4; i++)
#pragma unroll
    for (int j = 0; j < 4; j++) {
      const int row0 = bm0 + wr * 64 + i * 16 + g * 4;
      const int col  = bn0 + wc * 64 + j * 16 + cl;
      const float bb = bias[col];
      f32x4 v = acc[i][j];
      if (MODE == 0) {
        u16* o = (u16*)outp;
#pragma unroll
        for (int q = 0; q < 4; q++) o[(size_t)(row0 + q) * CH + col] = f2bf(v[q] + bb);
      } else if (MODE == 1) {
        u16* o = (u16*)outp;
        ushort4 pk;
        pk.x = f2bf(v[0] + bb); pk.y = f2bf(v[1] + bb);
        pk.z = f2bf(v[2] + bb); pk.w = f2bf(v[3] + bb);
        *(ushort4*)(o + (size_t)col * MTOT + row0) = pk;
      } else {
        float* o = (float*)outp;
#pragma unroll
        for (int q = 0; q < 4; q++) o[(size_t)(row0 + q) * CH + col] = v[q] + bb;
      }
    }
}

// ---------------------------------------------------------------------------
// Fused scores -> entmax(1.5, bisect) -> PV.
// 256 thr (4 waves), 16 Q-rows per block.  Scores: 16 chunks of 64 K-rows,
// double-buffered staging (fenced raw barriers, counted vmcnt), XOR-swizzled
// LDS.  Wave w owns Q-rows 4w..4w+3 for bisection (xa[4][16] in regs, fully
// unrolled => static indexing).  PV: p recomputed per chunk from xa/tau.
// ---------------------------------------------------------------------------
__global__ __launch_bounds__(256, 3) void fused_attn(
    const u16* __restrict__ q, const u16* __restrict__ k,
    const u16* __restrict__ vt, float* __restrict__ attn,
    u16* __restrict__ o)
{
  __shared__ u16  qt[16 * 64];        // 2 KB   (Q rows, swizzled)
  __shared__ u16  kvb[2][64 * 64];    // 16 KB  (K/V chunk double buffer)
  __shared__ float scb[16 * 68];      // 4.3 KB (score bounce, padded)
  __shared__ u16  pcb[16 * 64];       // 2 KB   (P chunk bf16, swizzled)

  const int t = threadIdx.x;
  const int w = t >> 6, lane = t & 63;
  const int cl = lane & 15, g = lane >> 4;
  const int n0 = blockIdx.x * 16;
  const int bh = blockIdx.y;
  const int b = bh >> 4, h = bh & 15;
  const int r0 = w * 4;

  const u16* qb = q  + ((size_t)(b * SEQ + n0) * CH + h * DH);
  const u16* kb = k  + ((size_t)(b * SEQ) * CH + h * DH);
  const u16* vb = vt + ((size_t)(h * DH) * MTOT + b * SEQ);

  const int srow = t >> 3;                                    // 0..31
  const int scol = (((t & 7) * 16) ^ ((srow & 7) << 4)) >> 1; // u16 elems (inv-swizzled src)

  if (t < 128)
    g2l16(qt + t * 8, qb + (size_t)srow * CH + scol);
  g2l16(kvb[0] + t * 8,        kb + (size_t)srow * CH + scol);
  g2l16(kvb[0] + 2048 + t * 8, kb + (size_t)(srow + 32) * CH + scol);

  float xa[4][16];

  // ---- scores: 16 chunks of 64 K-rows, 2-phase pipeline ----
#pragma unroll
  for (int c = 0; c < 16; ++c) {
    const int cur = c & 1;
    if (c < 15) {
      const u16* kc = kb + (size_t)(64 * (c + 1)) * CH;
      g2l16(kvb[cur ^ 1] + t * 8,        kc + (size_t)srow * CH + scol);
      g2l16(kvb[cur ^ 1] + 2048 + t * 8, kc + (size_t)(srow + 32) * CH + scol);
    }
    WAIT_LGKM0();                       // own scb reads hw-complete
    if (c < 15) { WAIT_VM2(); } else { WAIT_VM0(); }
    BAR();                              // kv[cur] staged for all waves
    f32x4 sa = {};
#pragma unroll
    for (int ks = 0; ks < 2; ++ks) {
      bf16x8 aq = ldfrag(qt, cl, ks * 64 + g * 16);
      bf16x8 bk = ldfrag(kvb[cur], w * 16 + cl, ks * 64 + g * 16);
      sa = __builtin_amdgcn_mfma_f32_16x16x32_bf16(aq, bk, sa, 0, 0, 0);
    }
#pragma unroll
    for (int qq = 0; qq < 4; ++qq)
      scb[(g * 4 + qq) * 68 + w * 16 + cl] = sa[qq] * 0.0625f;  // (1/8)*(alpha-1)
    WAIT_LGKM0();                       // scb writes + kv reads hw-complete
    BAR();                              // scb visible
#pragma unroll
    for (int r = 0; r < 4; ++r)
      xa[r][c] = scb[(r0 + r) * 68 + lane];
  }

  // prefetch V chunk 0 (latency hides under entmax VALU)
  g2l16(kvb[0] + t * 8,        vb + (size_t)srow * MTOT + scol);
  g2l16(kvb[0] + 2048 + t * 8, vb + (size_t)(srow + 32) * MTOT + scol);

  // ---- entmax bisection (alpha=1.5), 4 rows/wave, all in registers ----
  float tlo[4], flo[4], tm[4];
#pragma unroll
  for (int r = 0; r < 4; ++r) {
    float m = xa[r][0];
#pragma unroll
    for (int j = 1; j < 16; ++j) m = fmaxf(m, xa[r][j]);
#pragma unroll
    for (int off = 1; off < 64; off <<= 1) m = fmaxf(m, __shfl_xor(m, off));
    tlo[r] = m - 1.0f;
    float s = 0.f;
#pragma unroll
    for (int j = 0; j < 16; ++j) { float d = fmaxf(xa[r][j] - tlo[r], 0.f); s = fmaf(d, d, s); }
#pragma unroll
    for (int off = 1; off < 64; off <<= 1) s += __shfl_xor(s, off);
    flo[r] = s - 1.0f;
    tm[r] = tlo[r];
  }
  float dm = 0.96875f;                  // 1 - (1/1024)^0.5
  for (int it = 0; it < 26; ++it) {
    dm *= 0.5f;
    float s[4];
#pragma unroll
    for (int r = 0; r < 4; ++r) {
      tm[r] = tlo[r] + dm;
      float ss = 0.f;
#pragma unroll
      for (int j = 0; j < 16; ++j) { float d = fmaxf(xa[r][j] - tm[r], 0.f); ss = fmaf(d, d, ss); }
      s[r] = ss;
    }
#pragma unroll
    for (int off = 1; off < 64; off <<= 1) {
#pragma unroll
      for (int r = 0; r < 4; ++r) s[r] += __shfl_xor(s[r], off);
    }
#pragma unroll
    for (int r = 0; r < 4; ++r)
      if ((s[r] - 1.0f) * flo[r] >= 0.f) tlo[r] = tm[r];
  }
  float inv[4];
#pragma unroll
  for (int r = 0; r < 4; ++r) {
    float s2 = 0.f;
#pragma unroll
    for (int j = 0; j < 16; ++j) { float d = fmaxf(xa[r][j] - tm[r], 0.f); s2 = fmaf(d, d, s2); }
#pragma unroll
    for (int off = 1; off < 64; off <<= 1) s2 += __shfl_xor(s2, off);
    inv[r] = 1.0f / s2;
  }

  // ---- PV: 16 chunks of 64 V-rows, same 2-phase pipeline ----
  f32x4 pv = {};
  float* ab = attn + (size_t)bh * SEQ * SEQ + (size_t)(n0 + r0) * SEQ;
#pragma unroll
  for (int c = 0; c < 16; ++c) {
    const int cur = c & 1;
    if (c < 15) {
      const u16* vc = vb + 64 * (c + 1);
      g2l16(kvb[cur ^ 1] + t * 8,        vc + (size_t)srow * MTOT + scol);
      g2l16(kvb[cur ^ 1] + 2048 + t * 8, vc + (size_t)(srow + 32) * MTOT + scol);
    }
    float pval[4];
#pragma unroll
    for (int r = 0; r < 4; ++r) {
      float d = fmaxf(xa[r][c] - tm[r], 0.f);
      pval[r] = d * d * inv[r];
      const int row = r0 + r;
      *(u16*)((char*)pcb + row * 128 + ((lane * 2) ^ ((row & 7) << 4))) = f2bf(pval[r]);
    }
    WAIT_LGKM0();                       // pcb writes + prev reads hw-complete
    if (c < 15) { WAIT_VM2(); } else { WAIT_VM0(); }
    BAR();                              // pcb + V[cur] ready
#pragma unroll
    for (int ks = 0; ks < 2; ++ks) {
      bf16x8 ap  = ldfrag(pcb, cl, ks * 64 + g * 16);
      bf16x8 bv_ = ldfrag(kvb[cur], w * 16 + cl, ks * 64 + g * 16);
      pv = __builtin_amdgcn_mfma_f32_16x16x32_bf16(ap, bv_, pv, 0, 0, 0);
    }
#pragma unroll
    for (int r = 0; r < 4; ++r)
      ab[(size_t)r * SEQ + c * 64 + lane] = pval[r];
    WAIT_LGKM0();                       // frag reads hw-complete before reuse
    BAR();                              // all reads of pcb/kv[cur] done
  }

  u16* ob = o + (size_t)(b * SEQ + n0 + g * 4) * CH + h * DH + w * 16 + cl;
#pragma unroll
  for (int qq = 0; qq < 4; ++qq)
    ob[(size_t)qq * CH] = f2bf(pv[qq]);
}

// ---------------------------------------------------------------------------
extern "C" void kernel_launch(void* const* d_in, const int* in_sizes, int n_in,
                              void* d_out, int out_size, void* d_ws, size_t ws_size,
                              hipStream_t stream)
{
  const float* x  = (const float*)d_in[0];
  const float* Wq = (const float*)d_in[1];
  const float* bq = (const float*)d_in[2];
  const float* Wk = (const float*)d_in[3];
  const float* bk = (const float*)d_in[4];
  const float* Wv = (const float*)d_in[5];
  const float* bv = (const float*)d_in[6];
  const float* Wo = (const float*)d_in[7];
  const float* bo = (const float*)d_in[8];

  float* out0 = (float*)d_out;                        // [B,SEQ,CH] fp32
  float* attn = out0 + (size_t)NBAT * SEQ * CH;       // [B,H,SEQ,SEQ] fp32

  const size_t T = (size_t)MTOT * CH;                 // 4M elems
  u16* xb  = (u16*)d_ws;
  u16* qw  = xb  + T;
  u16* kw  = qw  + T;
  u16* vtw = kw  + T;
  u16* ow  = vtw + T;
  u16* wtq = ow  + T;
  u16* wtk = wtq + (size_t)CH * CH;
  u16* wtv = wtk + (size_t)CH * CH;
  u16* wto = wtv + (size_t)CH * CH;

  cvt_x<<<T / (4 * 256), 256, 0, stream>>>(x, xb);
  wt_bf16<<<dim3(16, 16), 256, 0, stream>>>(Wq, wtq);
  wt_bf16<<<dim3(16, 16), 256, 0, stream>>>(Wk, wtk);
  wt_bf16<<<dim3(16, 16), 256, 0, stream>>>(Wv, wtv);
  wt_bf16<<<dim3(16, 16), 256, 0, stream>>>(Wo, wto);

  gemm128<0><<<dim3(CH / 128, MTOT / 128), 256, 0, stream>>>(xb, wtq, bq, qw);
  gemm128<0><<<dim3(CH / 128, MTOT / 128), 256, 0, stream>>>(xb, wtk, bk, kw);
  gemm128<1><<<dim3(CH / 128, MTOT / 128), 256, 0, stream>>>(xb, wtv, bv, vtw);

  fused_attn<<<dim3(SEQ / 16, NBAT * NH), 256, 0, stream>>>(qw, kw, vtw, attn, ow);

  gemm128<2><<<dim3(CH / 128, MTOT / 128), 256, 0, stream>>>(ow, wto, bo, out0);
}

// Round 5
// 369.908 us; speedup vs baseline: 2.4567x; 1.0272x over previous
//
#include <hip/hip_runtime.h>
#include <hip/hip_bf16.h>
#include <stdint.h>

#define NBAT 4
#define SEQ 1024
#define CH 1024
#define NH 16
#define DH 64
#define MTOT (NBAT*SEQ)   // 4096

typedef __attribute__((ext_vector_type(8))) short bf16x8;
typedef __attribute__((ext_vector_type(4))) float f32x4;
typedef unsigned short u16;

// Raw barrier is NOT a compiler fence: bracket it (R2 lesson).
#define FENCE() asm volatile("" ::: "memory")
#define BAR() do { FENCE(); __builtin_amdgcn_s_barrier(); FENCE(); } while (0)
#define WAIT_VM1() asm volatile("s_waitcnt vmcnt(1)" ::: "memory")
#define WAIT_VM0() asm volatile("s_waitcnt vmcnt(0)" ::: "memory")
#define WAIT_LGKM0() asm volatile("s_waitcnt lgkmcnt(0)" ::: "memory")

__device__ __forceinline__ void g2l16(void* lds, const void* g) {
  __builtin_amdgcn_global_load_lds(
      (const __attribute__((address_space(1))) uint32_t*)g,
      (__attribute__((address_space(3))) uint32_t*)lds, 16, 0, 0);
}

__device__ __forceinline__ u16 f2bf(float f) {   // RNE float->bf16
  union { float f; uint32_t u; } v; v.f = f;
  uint32_t lsb = (v.u >> 16) & 1u;
  v.u += 0x7fffu + lsb;
  return (u16)(v.u >> 16);
}

// swizzled bf16x8 fragment read from a [rows][64 u16] LDS tile (128 B rows)
__device__ __forceinline__ bf16x8 ldfrag(const u16* base, int row, int koff) {
  return *(const bf16x8*)((const char*)base + row * 128 + (koff ^ ((row & 7) << 4)));
}

// ---------------------------------------------------------------------------
// x fp32 -> bf16 (4M elems)
// ---------------------------------------------------------------------------
__global__ __launch_bounds__(256) void cvt_x(const float* __restrict__ x,
                                             u16* __restrict__ xb) {
  int i = blockIdx.x * 256 + threadIdx.x;
  float4 v = ((const float4*)x)[i];
  ushort4 o;
  o.x = f2bf(v.x); o.y = f2bf(v.y); o.z = f2bf(v.z); o.w = f2bf(v.w);
  ((ushort4*)xb)[i] = o;
}

// ---------------------------------------------------------------------------
// W fp32 [1024][1024] -> Wt bf16 [n][k] (transposed), 64x64 tiles
// ---------------------------------------------------------------------------
__global__ __launch_bounds__(256) void wt_bf16(const float* __restrict__ W,
                                               u16* __restrict__ Wt) {
  __shared__ u16 tile[64][65];
  const int bi = blockIdx.x;      // n-tile
  const int bj = blockIdx.y;      // k-tile
  const int t = threadIdx.x;
  const int c4 = (t & 15) * 4, rr = t >> 4;
#pragma unroll
  for (int p = 0; p < 4; p++) {
    int r = p * 16 + rr;          // k within tile
    float4 v = *(const float4*)(W + (size_t)(bj * 64 + r) * CH + bi * 64 + c4);
    tile[r][c4 + 0] = f2bf(v.x); tile[r][c4 + 1] = f2bf(v.y);
    tile[r][c4 + 2] = f2bf(v.z); tile[r][c4 + 3] = f2bf(v.w);
  }
  __syncthreads();
  const int n = t >> 2, ks = (t & 3) * 16;
  u16 tmp[16];
#pragma unroll
  for (int i = 0; i < 16; i++) tmp[i] = tile[ks + i][n];
#pragma unroll
  for (int s = 0; s < 4; s++) {
    ushort4 o; o.x = tmp[4*s]; o.y = tmp[4*s+1]; o.z = tmp[4*s+2]; o.w = tmp[4*s+3];
    *(ushort4*)(Wt + (size_t)(bi * 64 + n) * CH + bj * 64 + ks + 4 * s) = o;
  }
}

// ---------------------------------------------------------------------------
// bf16 MFMA GEMM: C[4096][1024] = A[4096][1024] @ Bt^T + bias
// MODE 0: bf16 out [M][N]; MODE 1: bf16 out transposed [N][M]; MODE 2: fp32.
// ---------------------------------------------------------------------------
template<int MODE>
__global__ __launch_bounds__(256) void gemm128(
    const u16* __restrict__ A, const u16* __restrict__ Bt,
    const float* __restrict__ bias, void* __restrict__ outp)
{
  __shared__ u16 As[128 * 32];
  __shared__ u16 Bs[128 * 32];
  const int t = threadIdx.x;
  const int bn0 = blockIdx.x * 128;
  const int bm0 = blockIdx.y * 128;
  const int wid = t >> 6, lane = t & 63;
  const int wr = wid >> 1, wc = wid & 1;
  const int cl = lane & 15, g = lane >> 4;

  f32x4 acc[4][4] = {};
  const u16* ga = A  + (size_t)(bm0 + (t >> 2)) * CH + (t & 3) * 8;
  const u16* gb = Bt + (size_t)(bn0 + (t >> 2)) * CH + (t & 3) * 8;

  for (int k0 = 0; k0 < CH; k0 += 32) {
    g2l16(As + t * 8,        ga + k0);
    g2l16(As + 2048 + t * 8, ga + (size_t)64 * CH + k0);
    g2l16(Bs + t * 8,        gb + k0);
    g2l16(Bs + 2048 + t * 8, gb + (size_t)64 * CH + k0);
    __syncthreads();
    bf16x8 af[4], bfr[4];
#pragma unroll
    for (int f = 0; f < 4; f++) {
      af[f]  = *(const bf16x8*)(As + (wr * 64 + f * 16 + cl) * 32 + g * 8);
      bfr[f] = *(const bf16x8*)(Bs + (wc * 64 + f * 16 + cl) * 32 + g * 8);
    }
#pragma unroll
    for (int i = 0; i < 4; i++)
#pragma unroll
      for (int j = 0; j < 4; j++)
        acc[i][j] = __builtin_amdgcn_mfma_f32_16x16x32_bf16(af[i], bfr[j], acc[i][j], 0, 0, 0);
    __syncthreads();
  }

#pragma unroll
  for (int i = 0; i < 4; i++)
#pragma unroll
    for (int j = 0; j < 4; j++) {
      const int row0 = bm0 + wr * 64 + i * 16 + g * 4;
      const int col  = bn0 + wc * 64 + j * 16 + cl;
      const float bb = bias[col];
      f32x4 v = acc[i][j];
      if (MODE == 0) {
        u16* o = (u16*)outp;
#pragma unroll
        for (int q = 0; q < 4; q++) o[(size_t)(row0 + q) * CH + col] = f2bf(v[q] + bb);
      } else if (MODE == 1) {
        u16* o = (u16*)outp;
        ushort4 pk;
        pk.x = f2bf(v[0] + bb); pk.y = f2bf(v[1] + bb);
        pk.z = f2bf(v[2] + bb); pk.w = f2bf(v[3] + bb);
        *(ushort4*)(o + (size_t)col * MTOT + row0) = pk;
      } else {
        float* o = (float*)outp;
#pragma unroll
        for (int q = 0; q < 4; q++) o[(size_t)(row0 + q) * CH + col] = v[q] + bb;
      }
    }
}

// ---------------------------------------------------------------------------
// Fused scores -> entmax(1.5, Newton) -> PV.
// 512 thr (8 waves), 32 Q-rows per block, XCD-clustered 1D grid (2048).
// Scores: 16 chunks of 64 K-rows, double-buffered staging (fenced raw
// barriers, vmcnt(1) depth-2), XOR-swizzled LDS.  Wave w owns Q-rows
// 4w..4w+3; entmax tau via 8 monotone Newton iterations (f convex
// decreasing; start tau0 = max-1 => converges from the left).  PV: p
// recomputed per chunk from xa/tau, written fp32 to attn + bf16 to pcb.
// ---------------------------------------------------------------------------
__global__ __launch_bounds__(512, 3) void fused_attn(
    const u16* __restrict__ q, const u16* __restrict__ k,
    const u16* __restrict__ vt, float* __restrict__ attn,
    u16* __restrict__ o)
{
  __shared__ u16  qt[32 * 64];        // 4 KB   (Q rows, swizzled)
  __shared__ u16  kvb[2][64 * 64];    // 16 KB  (K/V chunk double buffer)
  __shared__ float scb[32 * 68];      // 8.7 KB (score bounce, padded)
  __shared__ u16  pcb[32 * 64];       // 4 KB   (P chunk bf16, swizzled)

  const int t = threadIdx.x;
  const int w = t >> 6, lane = t & 63;
  const int cl = lane & 15, g = lane >> 4;

  // XCD-clustered decode: lin%8 fixes bh%8 => per-XCD K/V set = 2 MB (L2-fit)
  const int lin = blockIdx.x;
  const int u = lin >> 3;
  const int n0 = (u & 31) * 32;
  const int bh = (lin & 7) | ((u >> 5) << 3);
  const int b = bh >> 4, h = bh & 15;
  const int r0 = w * 4;

  const u16* qb = q  + ((size_t)(b * SEQ + n0) * CH + h * DH);
  const u16* kb = k  + ((size_t)(b * SEQ) * CH + h * DH);
  const u16* vb = vt + ((size_t)(h * DH) * MTOT + b * SEQ);

  const int srow = t >> 3;                                    // 0..63
  const int scol = (((t & 7) * 16) ^ ((srow & 7) << 4)) >> 1; // u16 (inv-swz src)

  if (t < 256)
    g2l16(qt + t * 8, qb + (size_t)srow * CH + scol);
  g2l16(kvb[0] + t * 8, kb + (size_t)srow * CH + scol);

  float xa[4][16];
  const int swr = w >> 2, swc = w & 3;   // scores: q-tile, k-tile

  // ---- scores: 16 chunks of 64 K-rows, 2-phase pipeline ----
#pragma unroll
  for (int c = 0; c < 16; ++c) {
    const int cur = c & 1;
    if (c < 15)
      g2l16(kvb[cur ^ 1] + t * 8,
            kb + (size_t)(64 * (c + 1) + srow) * CH + scol);
    WAIT_LGKM0();                       // own scb reads hw-complete
    if (c < 15) { WAIT_VM1(); } else { WAIT_VM0(); }
    BAR();                              // kv[cur] staged for all waves
    f32x4 sa = {};
#pragma unroll
    for (int ks = 0; ks < 2; ++ks) {
      bf16x8 aq = ldfrag(qt, swr * 16 + cl, ks * 64 + g * 16);
      bf16x8 bk = ldfrag(kvb[cur], swc * 16 + cl, ks * 64 + g * 16);
      sa = __builtin_amdgcn_mfma_f32_16x16x32_bf16(aq, bk, sa, 0, 0, 0);
    }
#pragma unroll
    for (int qq = 0; qq < 4; ++qq)
      scb[(swr * 16 + g * 4 + qq) * 68 + swc * 16 + cl] = sa[qq] * 0.0625f;
    WAIT_LGKM0();                       // scb writes + kv reads hw-complete
    BAR();                              // scb visible
#pragma unroll
    for (int r = 0; r < 4; ++r)
      xa[r][c] = scb[(r0 + r) * 68 + lane];
  }

  // prefetch V chunk 0 (latency hides under Newton VALU)
  g2l16(kvb[0] + t * 8, vb + (size_t)srow * MTOT + scol);

  // ---- entmax tau via Newton (alpha=1.5), 4 rows/wave, in registers ----
  // f(tau) = sum (xa-tau)+^2 - 1: convex, decreasing.  tau0 = max-1 has
  // f >= 0; Newton is monotone from the left, quadratic terminal phase.
  float tau[4];
#pragma unroll
  for (int r = 0; r < 4; ++r) {
    float m = xa[r][0];
#pragma unroll
    for (int j = 1; j < 16; ++j) m = fmaxf(m, xa[r][j]);
#pragma unroll
    for (int off = 1; off < 64; off <<= 1) m = fmaxf(m, __shfl_xor(m, off));
    tau[r] = m - 1.0f;
  }
  for (int it = 0; it < 8; ++it) {
    float ss[4], sd[4];
#pragma unroll
    for (int r = 0; r < 4; ++r) {
      float s2 = 0.f, s1 = 0.f;
#pragma unroll
      for (int j = 0; j < 16; ++j) {
        float d = fmaxf(xa[r][j] - tau[r], 0.f);
        s2 = fmaf(d, d, s2); s1 += d;
      }
      ss[r] = s2; sd[r] = s1;
    }
#pragma unroll
    for (int off = 1; off < 64; off <<= 1) {
#pragma unroll
      for (int r = 0; r < 4; ++r) {
        ss[r] += __shfl_xor(ss[r], off);
        sd[r] += __shfl_xor(sd[r], off);
      }
    }
#pragma unroll
    for (int r = 0; r < 4; ++r)
      tau[r] += (ss[r] - 1.0f) / (sd[r] + sd[r]);
  }
  float inv[4];
#pragma unroll
  for (int r = 0; r < 4; ++r) {
    float s2 = 0.f;
#pragma unroll
    for (int j = 0; j < 16; ++j) { float d = fmaxf(xa[r][j] - tau[r], 0.f); s2 = fmaf(d, d, s2); }
#pragma unroll
    for (int off = 1; off < 64; off <<= 1) s2 += __shfl_xor(s2, off);
    inv[r] = 1.0f / s2;
  }

  // ---- PV: 16 chunks of 64 V-rows, same 2-phase pipeline ----
  const int pwr = w >> 2, pwc = w & 3;   // q-tile, dh-tile
  f32x4 pv = {};
  float* ab = attn + (size_t)bh * SEQ * SEQ + (size_t)(n0 + r0) * SEQ;
#pragma unroll
  for (int c = 0; c < 16; ++c) {
    const int cur = c & 1;
    if (c < 15)
      g2l16(kvb[cur ^ 1] + t * 8,
            vb + (size_t)srow * MTOT + 64 * (c + 1) + scol);
    float pval[4];
#pragma unroll
    for (int r = 0; r < 4; ++r) {
      float d = fmaxf(xa[r][c] - tau[r], 0.f);
      pval[r] = d * d * inv[r];
      const int row = r0 + r;
      *(u16*)((char*)pcb + row * 128 + ((lane * 2) ^ ((row & 7) << 4))) = f2bf(pval[r]);
    }
    WAIT_LGKM0();                       // pcb writes + prev reads hw-complete
    if (c < 15) { WAIT_VM1(); } else { WAIT_VM0(); }
    BAR();                              // pcb + V[cur] ready
#pragma unroll
    for (int ks = 0; ks < 2; ++ks) {
      bf16x8 ap  = ldfrag(pcb, pwr * 16 + cl, ks * 64 + g * 16);
      bf16x8 bv_ = ldfrag(kvb[cur], pwc * 16 + cl, ks * 64 + g * 16);
      pv = __builtin_amdgcn_mfma_f32_16x16x32_bf16(ap, bv_, pv, 0, 0, 0);
    }
#pragma unroll
    for (int r = 0; r < 4; ++r)
      ab[(size_t)r * SEQ + c * 64 + lane] = pval[r];
    WAIT_LGKM0();                       // frag reads hw-complete before reuse
    BAR();                              // all reads of pcb/kv[cur] done
  }

  u16* ob = o + (size_t)(b * SEQ + n0 + pwr * 16 + g * 4) * CH + h * DH + pwc * 16 + cl;
#pragma unroll
  for (int qq = 0; qq < 4; ++qq)
    ob[(size_t)qq * CH] = f2bf(pv[qq]);
}

// ---------------------------------------------------------------------------
extern "C" void kernel_launch(void* const* d_in, const int* in_sizes, int n_in,
                              void* d_out, int out_size, void* d_ws, size_t ws_size,
                              hipStream_t stream)
{
  const float* x  = (const float*)d_in[0];
  const float* Wq = (const float*)d_in[1];
  const float* bq = (const float*)d_in[2];
  const float* Wk = (const float*)d_in[3];
  const float* bk = (const float*)d_in[4];
  const float* Wv = (const float*)d_in[5];
  const float* bv = (const float*)d_in[6];
  const float* Wo = (const float*)d_in[7];
  const float* bo = (const float*)d_in[8];

  float* out0 = (float*)d_out;                        // [B,SEQ,CH] fp32
  float* attn = out0 + (size_t)NBAT * SEQ * CH;       // [B,H,SEQ,SEQ] fp32

  const size_t T = (size_t)MTOT * CH;                 // 4M elems
  u16* xb  = (u16*)d_ws;
  u16* qw  = xb  + T;
  u16* kw  = qw  + T;
  u16* vtw = kw  + T;
  u16* ow  = vtw + T;
  u16* wtq = ow  + T;
  u16* wtk = wtq + (size_t)CH * CH;
  u16* wtv = wtk + (size_t)CH * CH;
  u16* wto = wtv + (size_t)CH * CH;

  cvt_x<<<T / (4 * 256), 256, 0, stream>>>(x, xb);
  wt_bf16<<<dim3(16, 16), 256, 0, stream>>>(Wq, wtq);
  wt_bf16<<<dim3(16, 16), 256, 0, stream>>>(Wk, wtk);
  wt_bf16<<<dim3(16, 16), 256, 0, stream>>>(Wv, wtv);
  wt_bf16<<<dim3(16, 16), 256, 0, stream>>>(Wo, wto);

  gemm128<0><<<dim3(CH / 128, MTOT / 128), 256, 0, stream>>>(xb, wtq, bq, qw);
  gemm128<0><<<dim3(CH / 128, MTOT / 128), 256, 0, stream>>>(xb, wtk, bk, kw);
  gemm128<1><<<dim3(CH / 128, MTOT / 128), 256, 0, stream>>>(xb, wtv, bv, vtw);

  fused_attn<<<2048, 512, 0, stream>>>(qw, kw, vtw, attn, ow);

  gemm128<2><<<dim3(CH / 128, MTOT / 128), 256, 0, stream>>>(ow, wto, bo, out0);
}

// Round 6
// 302.454 us; speedup vs baseline: 3.0046x; 1.2230x over previous
//
#include <hip/hip_runtime.h>
#include <hip/hip_bf16.h>
#include <stdint.h>

#define NBAT 4
#define SEQ 1024
#define CH 1024
#define NH 16
#define DH 64
#define MTOT (NBAT*SEQ)   // 4096

typedef __attribute__((ext_vector_type(8))) short bf16x8;
typedef __attribute__((ext_vector_type(4))) float f32x4;
typedef unsigned short u16;

// Raw barrier is NOT a compiler fence: bracket it (R2 lesson).
#define FENCE() asm volatile("" ::: "memory")
#define BAR() do { FENCE(); __builtin_amdgcn_s_barrier(); FENCE(); } while (0)
#define WAIT_VM0() asm volatile("s_waitcnt vmcnt(0)" ::: "memory")
#define WAIT_VM2() asm volatile("s_waitcnt vmcnt(2)" ::: "memory")
#define WAIT_VM6() asm volatile("s_waitcnt vmcnt(6)" ::: "memory")
#define WAIT_LGKM0() asm volatile("s_waitcnt lgkmcnt(0)" ::: "memory")

__device__ __forceinline__ void g2l16(void* lds, const void* g) {
  __builtin_amdgcn_global_load_lds(
      (const __attribute__((address_space(1))) uint32_t*)g,
      (__attribute__((address_space(3))) uint32_t*)lds, 16, 0, 0);
}

__device__ __forceinline__ u16 f2bf(float f) {   // RNE float->bf16
  union { float f; uint32_t u; } v; v.f = f;
  uint32_t lsb = (v.u >> 16) & 1u;
  v.u += 0x7fffu + lsb;
  return (u16)(v.u >> 16);
}

// swizzled bf16x8 fragment read from a [rows][64 u16] LDS tile (128 B rows)
__device__ __forceinline__ bf16x8 ldfrag(const u16* base, int row, int koff) {
  return *(const bf16x8*)((const char*)base + row * 128 + (koff ^ ((row & 7) << 4)));
}

// ---------------------------------------------------------------------------
// x fp32 -> bf16 (4M elems)
// ---------------------------------------------------------------------------
__global__ __launch_bounds__(256) void cvt_x(const float* __restrict__ x,
                                             u16* __restrict__ xb) {
  int i = blockIdx.x * 256 + threadIdx.x;
  float4 v = ((const float4*)x)[i];
  ushort4 o;
  o.x = f2bf(v.x); o.y = f2bf(v.y); o.z = f2bf(v.z); o.w = f2bf(v.w);
  ((ushort4*)xb)[i] = o;
}

// ---------------------------------------------------------------------------
// W fp32 [1024][1024] -> Wt bf16 [n][k] (transposed), 64x64 tiles
// ---------------------------------------------------------------------------
__global__ __launch_bounds__(256) void wt_bf16(const float* __restrict__ W,
                                               u16* __restrict__ Wt) {
  __shared__ u16 tile[64][65];
  const int bi = blockIdx.x;      // n-tile
  const int bj = blockIdx.y;      // k-tile
  const int t = threadIdx.x;
  const int c4 = (t & 15) * 4, rr = t >> 4;
#pragma unroll
  for (int p = 0; p < 4; p++) {
    int r = p * 16 + rr;          // k within tile
    float4 v = *(const float4*)(W + (size_t)(bj * 64 + r) * CH + bi * 64 + c4);
    tile[r][c4 + 0] = f2bf(v.x); tile[r][c4 + 1] = f2bf(v.y);
    tile[r][c4 + 2] = f2bf(v.z); tile[r][c4 + 3] = f2bf(v.w);
  }
  __syncthreads();
  const int n = t >> 2, ks = (t & 3) * 16;
  u16 tmp[16];
#pragma unroll
  for (int i = 0; i < 16; i++) tmp[i] = tile[ks + i][n];
#pragma unroll
  for (int s = 0; s < 4; s++) {
    ushort4 o; o.x = tmp[4*s]; o.y = tmp[4*s+1]; o.z = tmp[4*s+2]; o.w = tmp[4*s+3];
    *(ushort4*)(Wt + (size_t)(bi * 64 + n) * CH + bj * 64 + ks + 4 * s) = o;
  }
}

// ---------------------------------------------------------------------------
// bf16 MFMA GEMM: C[4096][1024] = A[4096][1024] @ Bt^T + bias
// MODE 0: bf16 out [M][N]; MODE 1: bf16 out transposed [N][M]; MODE 2: fp32.
// ---------------------------------------------------------------------------
template<int MODE>
__global__ __launch_bounds__(256) void gemm128(
    const u16* __restrict__ A, const u16* __restrict__ Bt,
    const float* __restrict__ bias, void* __restrict__ outp)
{
  __shared__ u16 As[128 * 32];
  __shared__ u16 Bs[128 * 32];
  const int t = threadIdx.x;
  const int bn0 = blockIdx.x * 128;
  const int bm0 = blockIdx.y * 128;
  const int wid = t >> 6, lane = t & 63;
  const int wr = wid >> 1, wc = wid & 1;
  const int cl = lane & 15, g = lane >> 4;

  f32x4 acc[4][4] = {};
  const u16* ga = A  + (size_t)(bm0 + (t >> 2)) * CH + (t & 3) * 8;
  const u16* gb = Bt + (size_t)(bn0 + (t >> 2)) * CH + (t & 3) * 8;

  for (int k0 = 0; k0 < CH; k0 += 32) {
    g2l16(As + t * 8,        ga + k0);
    g2l16(As + 2048 + t * 8, ga + (size_t)64 * CH + k0);
    g2l16(Bs + t * 8,        gb + k0);
    g2l16(Bs + 2048 + t * 8, gb + (size_t)64 * CH + k0);
    __syncthreads();
    bf16x8 af[4], bfr[4];
#pragma unroll
    for (int f = 0; f < 4; f++) {
      af[f]  = *(const bf16x8*)(As + (wr * 64 + f * 16 + cl) * 32 + g * 8);
      bfr[f] = *(const bf16x8*)(Bs + (wc * 64 + f * 16 + cl) * 32 + g * 8);
    }
#pragma unroll
    for (int i = 0; i < 4; i++)
#pragma unroll
      for (int j = 0; j < 4; j++)
        acc[i][j] = __builtin_amdgcn_mfma_f32_16x16x32_bf16(af[i], bfr[j], acc[i][j], 0, 0, 0);
    __syncthreads();
  }

#pragma unroll
  for (int i = 0; i < 4; i++)
#pragma unroll
    for (int j = 0; j < 4; j++) {
      const int row0 = bm0 + wr * 64 + i * 16 + g * 4;
      const int col  = bn0 + wc * 64 + j * 16 + cl;
      const float bb = bias[col];
      f32x4 v = acc[i][j];
      if (MODE == 0) {
        u16* o = (u16*)outp;
#pragma unroll
        for (int q = 0; q < 4; q++) o[(size_t)(row0 + q) * CH + col] = f2bf(v[q] + bb);
      } else if (MODE == 1) {
        u16* o = (u16*)outp;
        ushort4 pk;
        pk.x = f2bf(v[0] + bb); pk.y = f2bf(v[1] + bb);
        pk.z = f2bf(v[2] + bb); pk.w = f2bf(v[3] + bb);
        *(ushort4*)(o + (size_t)col * MTOT + row0) = pk;
      } else {
        float* o = (float*)outp;
#pragma unroll
        for (int q = 0; q < 4; q++) o[(size_t)(row0 + q) * CH + col] = v[q] + bb;
      }
    }
}

// ---------------------------------------------------------------------------
// Fused scores -> entmax(1.5, Newton) -> PV, barrier-minimal.
// 256 thr (4 waves), 16 Q-rows/block.  Row-replicated MFMA: A-fragment uses
// Q-row r0+(cl&3), so D reg qq = S[r0+qq][16j+cl] on all lanes; keeping
// subtile j==g lands scores directly in the per-lane entmax layout
// xa[qq][c] = S[r0+qq][64c+lane] -- no LDS transpose, no 2nd barrier.
// K/V staged via triple-buffered g2l16, ONE barrier per 64-chunk, counted
// vmcnt (VM2/VM6 schedule accounts for attn stores in the VMEM queue).
// PV uses the same replication with a wave-PRIVATE P bounce (lgkm only).
// ---------------------------------------------------------------------------
__global__ __launch_bounds__(256, 3) void fused_attn(
    const u16* __restrict__ q, const u16* __restrict__ k,
    const u16* __restrict__ vt, float* __restrict__ attn,
    u16* __restrict__ o)
{
  __shared__ u16 buf[3][64 * 64];   // 24 KB staging (K chunks, then V^T chunks)
  __shared__ u16 pcb[4 * 256];      // 2 KB, per-wave P bounce (4 rows x 64)

  const int t = threadIdx.x;
  const int w = t >> 6, lane = t & 63;
  const int cl = lane & 15, g = lane >> 4;

  // XCD-clustered decode: lin%8 fixes bh%8 => per-XCD K/V set = 2 MB (L2-fit)
  const int lin = blockIdx.x;
  const int u = lin >> 3;
  const int n0 = (u & 63) * 16;
  const int bh = (lin & 7) | ((u >> 6) << 3);
  const int b = bh >> 4, h = bh & 15;
  const int r0 = w * 4;

  const u16* qb = q  + ((size_t)(b * SEQ + n0) * CH + h * DH);
  const u16* kb = k  + ((size_t)(b * SEQ) * CH + h * DH);
  const u16* vb = vt + ((size_t)(h * DH) * MTOT + b * SEQ);

  // Replicated Q A-fragments (rows r0..r0+3 repeated): row cl -> r0+(cl&3)
  const bf16x8 aq0 = *(const bf16x8*)(qb + (size_t)(r0 + (cl & 3)) * CH + g * 8);
  const bf16x8 aq1 = *(const bf16x8*)(qb + (size_t)(r0 + (cl & 3)) * CH + 32 + g * 8);

  // staging geometry: 256 thr x 16 B = 4 KB -> 2 g2l16 per 8 KB chunk
  const int srow = t >> 3;                                    // 0..31
  const int sbyte = ((t & 7) * 16) ^ ((srow & 7) << 4);       // inv-swz src
  const int scol = sbyte >> 1;                                // u16 units

  // prologue: stage K chunks 0,1
  g2l16(buf[0] + t * 8,        kb + (size_t)srow * CH + scol);
  g2l16(buf[0] + 2048 + t * 8, kb + (size_t)(srow + 32) * CH + scol);
  g2l16(buf[1] + t * 8,        kb + (size_t)(64 + srow) * CH + scol);
  g2l16(buf[1] + 2048 + t * 8, kb + (size_t)(64 + srow + 32) * CH + scol);

  float xa[4][16];

  // ---- scores: 16 chunks of 64 K-rows, 1 barrier/chunk, depth-2 prefetch ----
#pragma unroll
  for (int c = 0; c < 16; ++c) {
    WAIT_LGKM0();                        // my ds reads of prev buf complete
    if (c < 15) { WAIT_VM2(); } else { WAIT_VM0(); }
    BAR();                               // chunk c staged by ALL threads
    if (c + 2 < 16) {
      const u16* kc = kb + (size_t)(64 * (c + 2)) * CH;
      u16* d = buf[(c + 2) % 3];
      g2l16(d + t * 8,        kc + (size_t)srow * CH + scol);
      g2l16(d + 2048 + t * 8, kc + (size_t)(srow + 32) * CH + scol);
    }
    const u16* kc = buf[c % 3];
    f32x4 sc0 = {}, sc1 = {}, sc2 = {}, sc3 = {};
    sc0 = __builtin_amdgcn_mfma_f32_16x16x32_bf16(aq0, ldfrag(kc, cl,      g * 16), sc0, 0, 0, 0);
    sc0 = __builtin_amdgcn_mfma_f32_16x16x32_bf16(aq1, ldfrag(kc, cl,      64 + g * 16), sc0, 0, 0, 0);
    sc1 = __builtin_amdgcn_mfma_f32_16x16x32_bf16(aq0, ldfrag(kc, 16 + cl, g * 16), sc1, 0, 0, 0);
    sc1 = __builtin_amdgcn_mfma_f32_16x16x32_bf16(aq1, ldfrag(kc, 16 + cl, 64 + g * 16), sc1, 0, 0, 0);
    sc2 = __builtin_amdgcn_mfma_f32_16x16x32_bf16(aq0, ldfrag(kc, 32 + cl, g * 16), sc2, 0, 0, 0);
    sc2 = __builtin_amdgcn_mfma_f32_16x16x32_bf16(aq1, ldfrag(kc, 32 + cl, 64 + g * 16), sc2, 0, 0, 0);
    sc3 = __builtin_amdgcn_mfma_f32_16x16x32_bf16(aq0, ldfrag(kc, 48 + cl, g * 16), sc3, 0, 0, 0);
    sc3 = __builtin_amdgcn_mfma_f32_16x16x32_bf16(aq1, ldfrag(kc, 48 + cl, 64 + g * 16), sc3, 0, 0, 0);
#pragma unroll
    for (int qq = 0; qq < 4; ++qq) {     // keep subtile j == g
      float v = sc0[qq];
      v = (g == 1) ? sc1[qq] : v;
      v = (g == 2) ? sc2[qq] : v;
      v = (g == 3) ? sc3[qq] : v;
      xa[qq][c] = v * 0.0625f;           // (1/8)*(alpha-1)
    }
  }

  // stage V chunks 0,1 (V^T rows = dh); latency hides under Newton
  g2l16(buf[1] + t * 8,        vb + (size_t)srow * MTOT + scol);
  g2l16(buf[1] + 2048 + t * 8, vb + (size_t)(srow + 32) * MTOT + scol);
  g2l16(buf[2] + t * 8,        vb + (size_t)srow * MTOT + 64 + scol);
  g2l16(buf[2] + 2048 + t * 8, vb + (size_t)(srow + 32) * MTOT + 64 + scol);

  // ---- entmax tau via Newton (alpha=1.5), 4 rows/wave, in registers ----
  float tau[4];
#pragma unroll
  for (int r = 0; r < 4; ++r) {
    float m = xa[r][0];
#pragma unroll
    for (int j = 1; j < 16; ++j) m = fmaxf(m, xa[r][j]);
#pragma unroll
    for (int off = 1; off < 64; off <<= 1) m = fmaxf(m, __shfl_xor(m, off));
    tau[r] = m - 1.0f;
  }
  for (int it = 0; it < 8; ++it) {
    float ss[4], sd[4];
#pragma unroll
    for (int r = 0; r < 4; ++r) {
      float s2 = 0.f, s1 = 0.f;
#pragma unroll
      for (int j = 0; j < 16; ++j) {
        float d = fmaxf(xa[r][j] - tau[r], 0.f);
        s2 = fmaf(d, d, s2); s1 += d;
      }
      ss[r] = s2; sd[r] = s1;
    }
#pragma unroll
    for (int off = 1; off < 64; off <<= 1) {
#pragma unroll
      for (int r = 0; r < 4; ++r) {
        ss[r] += __shfl_xor(ss[r], off);
        sd[r] += __shfl_xor(sd[r], off);
      }
    }
#pragma unroll
    for (int r = 0; r < 4; ++r)
      tau[r] += (ss[r] - 1.0f) / (sd[r] + sd[r]);
  }
  float inv[4];
#pragma unroll
  for (int r = 0; r < 4; ++r) {
    float s2 = 0.f;
#pragma unroll
    for (int j = 0; j < 16; ++j) { float d = fmaxf(xa[r][j] - tau[r], 0.f); s2 = fmaf(d, d, s2); }
#pragma unroll
    for (int off = 1; off < 64; off <<= 1) s2 += __shfl_xor(s2, off);
    inv[r] = 1.0f / s2;
  }

  // ---- PV: 16 chunks of 64 V-rows, 1 barrier/chunk ----
  char* pw = (char*)pcb + w * 512;       // wave-private P bounce
  f32x4 pva0 = {}, pva1 = {}, pva2 = {}, pva3 = {};
  float* ab = attn + (size_t)bh * SEQ * SEQ + (size_t)(n0 + r0) * SEQ;
#pragma unroll
  for (int vc = 0; vc < 16; ++vc) {
    float pval[4];
#pragma unroll
    for (int r = 0; r < 4; ++r) {
      float d = fmaxf(xa[r][vc] - tau[r], 0.f);
      pval[r] = d * d * inv[r];
      *(u16*)(pw + r * 128 + ((lane * 2) ^ (r << 4))) = f2bf(pval[r]);
    }
    WAIT_LGKM0();                        // pcb writes + prev frag reads done
    if (vc == 0) { WAIT_VM2(); } else { WAIT_VM6(); }
    BAR();                               // V chunk vc staged for all threads
    if (vc + 2 < 16) {
      const u16* vc2 = vb + (size_t)64 * (vc + 2);
      u16* d = buf[(16 + vc + 2) % 3];
      g2l16(d + t * 8,        vc2 + (size_t)srow * MTOT + scol);
      g2l16(d + 2048 + t * 8, vc2 + (size_t)(srow + 32) * MTOT + scol);
    }
    const u16* vbu = buf[(16 + vc) % 3];
    const bf16x8 ap0 = *(const bf16x8*)(pw + (cl & 3) * 128 + ((g * 16) ^ ((cl & 3) << 4)));
    const bf16x8 ap1 = *(const bf16x8*)(pw + (cl & 3) * 128 + ((64 + g * 16) ^ ((cl & 3) << 4)));
    pva0 = __builtin_amdgcn_mfma_f32_16x16x32_bf16(ap0, ldfrag(vbu, cl,      g * 16), pva0, 0, 0, 0);
    pva0 = __builtin_amdgcn_mfma_f32_16x16x32_bf16(ap1, ldfrag(vbu, cl,      64 + g * 16), pva0, 0, 0, 0);
    pva1 = __builtin_amdgcn_mfma_f32_16x16x32_bf16(ap0, ldfrag(vbu, 16 + cl, g * 16), pva1, 0, 0, 0);
    pva1 = __builtin_amdgcn_mfma_f32_16x16x32_bf16(ap1, ldfrag(vbu, 16 + cl, 64 + g * 16), pva1, 0, 0, 0);
    pva2 = __builtin_amdgcn_mfma_f32_16x16x32_bf16(ap0, ldfrag(vbu, 32 + cl, g * 16), pva2, 0, 0, 0);
    pva2 = __builtin_amdgcn_mfma_f32_16x16x32_bf16(ap1, ldfrag(vbu, 32 + cl, 64 + g * 16), pva2, 0, 0, 0);
    pva3 = __builtin_amdgcn_mfma_f32_16x16x32_bf16(ap0, ldfrag(vbu, 48 + cl, g * 16), pva3, 0, 0, 0);
    pva3 = __builtin_amdgcn_mfma_f32_16x16x32_bf16(ap1, ldfrag(vbu, 48 + cl, 64 + g * 16), pva3, 0, 0, 0);
#pragma unroll
    for (int r = 0; r < 4; ++r)
      ab[(size_t)r * SEQ + vc * 64 + lane] = pval[r];
  }

  // output: lane stores dh-subtile j2 == g  => column = h*DH + lane
  u16* ob = o + (size_t)(b * SEQ + n0 + r0) * CH + h * DH + lane;
#pragma unroll
  for (int qq = 0; qq < 4; ++qq) {
    float v = pva0[qq];
    v = (g == 1) ? pva1[qq] : v;
    v = (g == 2) ? pva2[qq] : v;
    v = (g == 3) ? pva3[qq] : v;
    ob[(size_t)qq * CH] = f2bf(v);
  }
}

// ---------------------------------------------------------------------------
extern "C" void kernel_launch(void* const* d_in, const int* in_sizes, int n_in,
                              void* d_out, int out_size, void* d_ws, size_t ws_size,
                              hipStream_t stream)
{
  const float* x  = (const float*)d_in[0];
  const float* Wq = (const float*)d_in[1];
  const float* bq = (const float*)d_in[2];
  const float* Wk = (const float*)d_in[3];
  const float* bk = (const float*)d_in[4];
  const float* Wv = (const float*)d_in[5];
  const float* bv = (const float*)d_in[6];
  const float* Wo = (const float*)d_in[7];
  const float* bo = (const float*)d_in[8];

  float* out0 = (float*)d_out;                        // [B,SEQ,CH] fp32
  float* attn = out0 + (size_t)NBAT * SEQ * CH;       // [B,H,SEQ,SEQ] fp32

  const size_t T = (size_t)MTOT * CH;                 // 4M elems
  u16* xb  = (u16*)d_ws;
  u16* qw  = xb  + T;
  u16* kw  = qw  + T;
  u16* vtw = kw  + T;
  u16* ow  = vtw + T;
  u16* wtq = ow  + T;
  u16* wtk = wtq + (size_t)CH * CH;
  u16* wtv = wtk + (size_t)CH * CH;
  u16* wto = wtv + (size_t)CH * CH;

  cvt_x<<<T / (4 * 256), 256, 0, stream>>>(x, xb);
  wt_bf16<<<dim3(16, 16), 256, 0, stream>>>(Wq, wtq);
  wt_bf16<<<dim3(16, 16), 256, 0, stream>>>(Wk, wtk);
  wt_bf16<<<dim3(16, 16), 256, 0, stream>>>(Wv, wtv);
  wt_bf16<<<dim3(16, 16), 256, 0, stream>>>(Wo, wto);

  gemm128<0><<<dim3(CH / 128, MTOT / 128), 256, 0, stream>>>(xb, wtq, bq, qw);
  gemm128<0><<<dim3(CH / 128, MTOT / 128), 256, 0, stream>>>(xb, wtk, bk, kw);
  gemm128<1><<<dim3(CH / 128, MTOT / 128), 256, 0, stream>>>(xb, wtv, bv, vtw);

  fused_attn<<<4096, 256, 0, stream>>>(qw, kw, vtw, attn, ow);

  gemm128<2><<<dim3(CH / 128, MTOT / 128), 256, 0, stream>>>(ow, wto, bo, out0);
}

// Round 7
// 288.686 us; speedup vs baseline: 3.1479x; 1.0477x over previous
//
#include <hip/hip_runtime.h>
#include <hip/hip_bf16.h>
#include <stdint.h>

#define NBAT 4
#define SEQ 1024
#define CH 1024
#define NH 16
#define DH 64
#define MTOT (NBAT*SEQ)   // 4096

typedef __attribute__((ext_vector_type(8))) short bf16x8;
typedef __attribute__((ext_vector_type(4))) float f32x4;
typedef unsigned short u16;

// Raw barrier is NOT a compiler fence: bracket it (R2 lesson).
#define FENCE() asm volatile("" ::: "memory")
#define BAR() do { FENCE(); __builtin_amdgcn_s_barrier(); FENCE(); } while (0)
#define WAIT_VM0() asm volatile("s_waitcnt vmcnt(0)" ::: "memory")
#define WAIT_VM2() asm volatile("s_waitcnt vmcnt(2)" ::: "memory")
#define WAIT_VM6() asm volatile("s_waitcnt vmcnt(6)" ::: "memory")
#define WAIT_LGKM0() asm volatile("s_waitcnt lgkmcnt(0)" ::: "memory")

__device__ __forceinline__ void g2l16(void* lds, const void* g) {
  __builtin_amdgcn_global_load_lds(
      (const __attribute__((address_space(1))) uint32_t*)g,
      (__attribute__((address_space(3))) uint32_t*)lds, 16, 0, 0);
}

__device__ __forceinline__ u16 f2bf(float f) {   // RNE float->bf16
  union { float f; uint32_t u; } v; v.f = f;
  uint32_t lsb = (v.u >> 16) & 1u;
  v.u += 0x7fffu + lsb;
  return (u16)(v.u >> 16);
}

// swizzled bf16x8 fragment read from a [rows][64 u16] LDS tile (128 B rows)
__device__ __forceinline__ bf16x8 ldfrag(const u16* base, int row, int koff) {
  return *(const bf16x8*)((const char*)base + row * 128 + (koff ^ ((row & 7) << 4)));
}

// ---------------------------------------------------------------------------
// x fp32 -> bf16 (4M elems)
// ---------------------------------------------------------------------------
__global__ __launch_bounds__(256) void cvt_x(const float* __restrict__ x,
                                             u16* __restrict__ xb) {
  int i = blockIdx.x * 256 + threadIdx.x;
  float4 v = ((const float4*)x)[i];
  ushort4 o;
  o.x = f2bf(v.x); o.y = f2bf(v.y); o.z = f2bf(v.z); o.w = f2bf(v.w);
  ((ushort4*)xb)[i] = o;
}

// ---------------------------------------------------------------------------
// W fp32 [1024][1024] -> Wt bf16 [n][k] (transposed), 64x64 tiles
// ---------------------------------------------------------------------------
__global__ __launch_bounds__(256) void wt_bf16(const float* __restrict__ W,
                                               u16* __restrict__ Wt) {
  __shared__ u16 tile[64][65];
  const int bi = blockIdx.x;      // n-tile
  const int bj = blockIdx.y;      // k-tile
  const int t = threadIdx.x;
  const int c4 = (t & 15) * 4, rr = t >> 4;
#pragma unroll
  for (int p = 0; p < 4; p++) {
    int r = p * 16 + rr;          // k within tile
    float4 v = *(const float4*)(W + (size_t)(bj * 64 + r) * CH + bi * 64 + c4);
    tile[r][c4 + 0] = f2bf(v.x); tile[r][c4 + 1] = f2bf(v.y);
    tile[r][c4 + 2] = f2bf(v.z); tile[r][c4 + 3] = f2bf(v.w);
  }
  __syncthreads();
  const int n = t >> 2, ks = (t & 3) * 16;
  u16 tmp[16];
#pragma unroll
  for (int i = 0; i < 16; i++) tmp[i] = tile[ks + i][n];
#pragma unroll
  for (int s = 0; s < 4; s++) {
    ushort4 o; o.x = tmp[4*s]; o.y = tmp[4*s+1]; o.z = tmp[4*s+2]; o.w = tmp[4*s+3];
    *(ushort4*)(Wt + (size_t)(bi * 64 + n) * CH + bj * 64 + ks + 4 * s) = o;
  }
}

// ---------------------------------------------------------------------------
// bf16 MFMA GEMM body: C[4096][1024] = A[4096][1024] @ Bt^T + bias
// MODE 0: bf16 out [M][N] (scaled); MODE 1: bf16 out transposed [N][M];
// MODE 2: fp32 out [M][N].
// ---------------------------------------------------------------------------
template<int MODE>
__device__ __forceinline__ void gemm_body(
    u16* As, u16* Bs,
    const u16* __restrict__ A, const u16* __restrict__ Bt,
    const float* __restrict__ bias, void* __restrict__ outp,
    float scale, int bn0, int bm0, int t)
{
  const int wid = t >> 6, lane = t & 63;
  const int wr = wid >> 1, wc = wid & 1;
  const int cl = lane & 15, g = lane >> 4;

  f32x4 acc[4][4] = {};
  const u16* ga = A  + (size_t)(bm0 + (t >> 2)) * CH + (t & 3) * 8;
  const u16* gb = Bt + (size_t)(bn0 + (t >> 2)) * CH + (t & 3) * 8;

  for (int k0 = 0; k0 < CH; k0 += 32) {
    g2l16(As + t * 8,        ga + k0);
    g2l16(As + 2048 + t * 8, ga + (size_t)64 * CH + k0);
    g2l16(Bs + t * 8,        gb + k0);
    g2l16(Bs + 2048 + t * 8, gb + (size_t)64 * CH + k0);
    __syncthreads();
    bf16x8 af[4], bfr[4];
#pragma unroll
    for (int f = 0; f < 4; f++) {
      af[f]  = *(const bf16x8*)(As + (wr * 64 + f * 16 + cl) * 32 + g * 8);
      bfr[f] = *(const bf16x8*)(Bs + (wc * 64 + f * 16 + cl) * 32 + g * 8);
    }
#pragma unroll
    for (int i = 0; i < 4; i++)
#pragma unroll
      for (int j = 0; j < 4; j++)
        acc[i][j] = __builtin_amdgcn_mfma_f32_16x16x32_bf16(af[i], bfr[j], acc[i][j], 0, 0, 0);
    __syncthreads();
  }

#pragma unroll
  for (int i = 0; i < 4; i++)
#pragma unroll
    for (int j = 0; j < 4; j++) {
      const int row0 = bm0 + wr * 64 + i * 16 + g * 4;
      const int col  = bn0 + wc * 64 + j * 16 + cl;
      const float bb = bias[col];
      f32x4 v = acc[i][j];
      if (MODE == 0) {
        u16* o = (u16*)outp;
#pragma unroll
        for (int q = 0; q < 4; q++) o[(size_t)(row0 + q) * CH + col] = f2bf((v[q] + bb) * scale);
      } else if (MODE == 1) {
        u16* o = (u16*)outp;
        ushort4 pk;
        pk.x = f2bf(v[0] + bb); pk.y = f2bf(v[1] + bb);
        pk.z = f2bf(v[2] + bb); pk.w = f2bf(v[3] + bb);
        *(ushort4*)(o + (size_t)col * MTOT + row0) = pk;
      } else {
        float* o = (float*)outp;
#pragma unroll
        for (int q = 0; q < 4; q++) o[(size_t)(row0 + q) * CH + col] = v[q] + bb;
      }
    }
}

// Q/K/V in one launch: grid.z selects target (3x blocks -> 3 blocks/CU MFMA overlap)
__global__ __launch_bounds__(256) void gemm_qkv(
    const u16* __restrict__ A,
    const u16* __restrict__ Wtq, const float* __restrict__ bq, u16* __restrict__ qo,
    const u16* __restrict__ Wtk, const float* __restrict__ bk, u16* __restrict__ ko,
    const u16* __restrict__ Wtv, const float* __restrict__ bv, u16* __restrict__ vo)
{
  __shared__ u16 As[128 * 32];
  __shared__ u16 Bs[128 * 32];
  const int t = threadIdx.x;
  const int bn0 = blockIdx.x * 128, bm0 = blockIdx.y * 128;
  if (blockIdx.z == 0)
    gemm_body<0>(As, Bs, A, Wtq, bq, qo, 0.0625f, bn0, bm0, t);   // pre-scaled Q
  else if (blockIdx.z == 1)
    gemm_body<0>(As, Bs, A, Wtk, bk, ko, 1.0f, bn0, bm0, t);
  else
    gemm_body<1>(As, Bs, A, Wtv, bv, vo, 1.0f, bn0, bm0, t);
}

__global__ __launch_bounds__(256) void gemm_out(
    const u16* __restrict__ A, const u16* __restrict__ Bt,
    const float* __restrict__ bias, float* __restrict__ outp)
{
  __shared__ u16 As[128 * 32];
  __shared__ u16 Bs[128 * 32];
  gemm_body<2>(As, Bs, A, Bt, bias, outp, 1.0f, blockIdx.x * 128, blockIdx.y * 128,
               threadIdx.x);
}

// ---------------------------------------------------------------------------
// Fused scores -> entmax(1.5, Newton) -> PV, barrier-minimal.
// 256 thr (4 waves), 16 Q-rows/block, 5 blocks/CU target.  Row-replicated
// MFMA lands scores directly in per-lane layout xa[qq][c] = S[r0+qq][64c+lane]
// (no LDS transpose).  K/V triple-buffered g2l16, ONE barrier per chunk,
// counted vmcnt (VM2/VM6 accounts for attn stores in the queue).  Q arrives
// pre-scaled by (1/8)*(alpha-1) from the projection.
// ---------------------------------------------------------------------------
__global__ __launch_bounds__(256, 5) void fused_attn(
    const u16* __restrict__ q, const u16* __restrict__ k,
    const u16* __restrict__ vt, float* __restrict__ attn,
    u16* __restrict__ o)
{
  __shared__ u16 buf[3][64 * 64];   // 24 KB staging (K chunks, then V^T chunks)
  __shared__ u16 pcb[4 * 256];      // 2 KB, per-wave P bounce (4 rows x 64)

  const int t = threadIdx.x;
  const int w = t >> 6, lane = t & 63;
  const int cl = lane & 15, g = lane >> 4;

  // XCD-clustered decode: lin%8 fixes bh%8 => per-XCD K/V set L2-resident
  const int lin = blockIdx.x;
  const int u = lin >> 3;
  const int n0 = (u & 63) * 16;
  const int bh = (lin & 7) | ((u >> 6) << 3);
  const int b = bh >> 4, h = bh & 15;
  const int r0 = w * 4;

  const u16* qb = q  + ((size_t)(b * SEQ + n0) * CH + h * DH);
  const u16* kb = k  + ((size_t)(b * SEQ) * CH + h * DH);
  const u16* vb = vt + ((size_t)(h * DH) * MTOT + b * SEQ);

  // Replicated Q A-fragments (rows r0..r0+3 repeated): row cl -> r0+(cl&3)
  const bf16x8 aq0 = *(const bf16x8*)(qb + (size_t)(r0 + (cl & 3)) * CH + g * 8);
  const bf16x8 aq1 = *(const bf16x8*)(qb + (size_t)(r0 + (cl & 3)) * CH + 32 + g * 8);

  // staging geometry: 256 thr x 16 B = 4 KB -> 2 g2l16 per 8 KB chunk
  const int srow = t >> 3;                                    // 0..31
  const int sbyte = ((t & 7) * 16) ^ ((srow & 7) << 4);       // inv-swz src
  const int scol = sbyte >> 1;                                // u16 units

  // prologue: stage K chunks 0,1
  g2l16(buf[0] + t * 8,        kb + (size_t)srow * CH + scol);
  g2l16(buf[0] + 2048 + t * 8, kb + (size_t)(srow + 32) * CH + scol);
  g2l16(buf[1] + t * 8,        kb + (size_t)(64 + srow) * CH + scol);
  g2l16(buf[1] + 2048 + t * 8, kb + (size_t)(64 + srow + 32) * CH + scol);

  float xa[4][16];

  // ---- scores: 16 chunks of 64 K-rows, 1 barrier/chunk, depth-2 prefetch ----
#pragma unroll
  for (int c = 0; c < 16; ++c) {
    WAIT_LGKM0();                        // my ds reads of prev buf complete
    if (c < 15) { WAIT_VM2(); } else { WAIT_VM0(); }
    BAR();                               // chunk c staged by ALL threads
    if (c + 2 < 16) {
      const u16* kc = kb + (size_t)(64 * (c + 2)) * CH;
      u16* d = buf[(c + 2) % 3];
      g2l16(d + t * 8,        kc + (size_t)srow * CH + scol);
      g2l16(d + 2048 + t * 8, kc + (size_t)(srow + 32) * CH + scol);
    }
    const u16* kc = buf[c % 3];
    f32x4 sc0 = {}, sc1 = {}, sc2 = {}, sc3 = {};
    sc0 = __builtin_amdgcn_mfma_f32_16x16x32_bf16(aq0, ldfrag(kc, cl,      g * 16), sc0, 0, 0, 0);
    sc0 = __builtin_amdgcn_mfma_f32_16x16x32_bf16(aq1, ldfrag(kc, cl,      64 + g * 16), sc0, 0, 0, 0);
    sc1 = __builtin_amdgcn_mfma_f32_16x16x32_bf16(aq0, ldfrag(kc, 16 + cl, g * 16), sc1, 0, 0, 0);
    sc1 = __builtin_amdgcn_mfma_f32_16x16x32_bf16(aq1, ldfrag(kc, 16 + cl, 64 + g * 16), sc1, 0, 0, 0);
    sc2 = __builtin_amdgcn_mfma_f32_16x16x32_bf16(aq0, ldfrag(kc, 32 + cl, g * 16), sc2, 0, 0, 0);
    sc2 = __builtin_amdgcn_mfma_f32_16x16x32_bf16(aq1, ldfrag(kc, 32 + cl, 64 + g * 16), sc2, 0, 0, 0);
    sc3 = __builtin_amdgcn_mfma_f32_16x16x32_bf16(aq0, ldfrag(kc, 48 + cl, g * 16), sc3, 0, 0, 0);
    sc3 = __builtin_amdgcn_mfma_f32_16x16x32_bf16(aq1, ldfrag(kc, 48 + cl, 64 + g * 16), sc3, 0, 0, 0);
#pragma unroll
    for (int qq = 0; qq < 4; ++qq) {     // keep subtile j == g
      float v = sc0[qq];
      v = (g == 1) ? sc1[qq] : v;
      v = (g == 2) ? sc2[qq] : v;
      v = (g == 3) ? sc3[qq] : v;
      xa[qq][c] = v;                     // Q pre-scaled: already *(1/8)*(a-1)
    }
  }

  // stage V chunks 0,1 (V^T rows = dh); latency hides under Newton
  g2l16(buf[1] + t * 8,        vb + (size_t)srow * MTOT + scol);
  g2l16(buf[1] + 2048 + t * 8, vb + (size_t)(srow + 32) * MTOT + scol);
  g2l16(buf[2] + t * 8,        vb + (size_t)srow * MTOT + 64 + scol);
  g2l16(buf[2] + 2048 + t * 8, vb + (size_t)(srow + 32) * MTOT + 64 + scol);

  // ---- entmax tau via Newton (alpha=1.5), 4 rows/wave, in registers ----
  float tau[4];
#pragma unroll
  for (int r = 0; r < 4; ++r) {
    float m = xa[r][0];
#pragma unroll
    for (int j = 1; j < 16; ++j) m = fmaxf(m, xa[r][j]);
#pragma unroll
    for (int off = 1; off < 64; off <<= 1) m = fmaxf(m, __shfl_xor(m, off));
    tau[r] = m - 1.0f;
  }
  for (int it = 0; it < 7; ++it) {
    float ss[4], sd[4];
#pragma unroll
    for (int r = 0; r < 4; ++r) {
      float s2 = 0.f, s1 = 0.f;
#pragma unroll
      for (int j = 0; j < 16; ++j) {
        float d = fmaxf(xa[r][j] - tau[r], 0.f);
        s2 = fmaf(d, d, s2); s1 += d;
      }
      ss[r] = s2; sd[r] = s1;
    }
#pragma unroll
    for (int off = 1; off < 64; off <<= 1) {
#pragma unroll
      for (int r = 0; r < 4; ++r) {
        ss[r] += __shfl_xor(ss[r], off);
        sd[r] += __shfl_xor(sd[r], off);
      }
    }
#pragma unroll
    for (int r = 0; r < 4; ++r)
      tau[r] += (ss[r] - 1.0f) / (sd[r] + sd[r]);
  }
  float inv[4];
#pragma unroll
  for (int r = 0; r < 4; ++r) {
    float s2 = 0.f;
#pragma unroll
    for (int j = 0; j < 16; ++j) { float d = fmaxf(xa[r][j] - tau[r], 0.f); s2 = fmaf(d, d, s2); }
#pragma unroll
    for (int off = 1; off < 64; off <<= 1) s2 += __shfl_xor(s2, off);
    inv[r] = 1.0f / s2;
  }

  // ---- PV: 16 chunks of 64 V-rows, 1 barrier/chunk ----
  char* pw = (char*)pcb + w * 512;       // wave-private P bounce
  f32x4 pva0 = {}, pva1 = {}, pva2 = {}, pva3 = {};
  float* ab = attn + (size_t)bh * SEQ * SEQ + (size_t)(n0 + r0) * SEQ;
#pragma unroll
  for (int vc = 0; vc < 16; ++vc) {
    float pval[4];
#pragma unroll
    for (int r = 0; r < 4; ++r) {
      float d = fmaxf(xa[r][vc] - tau[r], 0.f);
      pval[r] = d * d * inv[r];
      *(u16*)(pw + r * 128 + ((lane * 2) ^ (r << 4))) = f2bf(pval[r]);
    }
    WAIT_LGKM0();                        // pcb writes + prev frag reads done
    if (vc == 0) { WAIT_VM2(); } else { WAIT_VM6(); }
    BAR();                               // V chunk vc staged for all threads
    if (vc + 2 < 16) {
      const u16* vc2 = vb + (size_t)64 * (vc + 2);
      u16* d = buf[(16 + vc + 2) % 3];
      g2l16(d + t * 8,        vc2 + (size_t)srow * MTOT + scol);
      g2l16(d + 2048 + t * 8, vc2 + (size_t)(srow + 32) * MTOT + scol);
    }
    const u16* vbu = buf[(16 + vc) % 3];
    const bf16x8 ap0 = *(const bf16x8*)(pw + (cl & 3) * 128 + ((g * 16) ^ ((cl & 3) << 4)));
    const bf16x8 ap1 = *(const bf16x8*)(pw + (cl & 3) * 128 + ((64 + g * 16) ^ ((cl & 3) << 4)));
    pva0 = __builtin_amdgcn_mfma_f32_16x16x32_bf16(ap0, ldfrag(vbu, cl,      g * 16), pva0, 0, 0, 0);
    pva0 = __builtin_amdgcn_mfma_f32_16x16x32_bf16(ap1, ldfrag(vbu, cl,      64 + g * 16), pva0, 0, 0, 0);
    pva1 = __builtin_amdgcn_mfma_f32_16x16x32_bf16(ap0, ldfrag(vbu, 16 + cl, g * 16), pva1, 0, 0, 0);
    pva1 = __builtin_amdgcn_mfma_f32_16x16x32_bf16(ap1, ldfrag(vbu, 16 + cl, 64 + g * 16), pva1, 0, 0, 0);
    pva2 = __builtin_amdgcn_mfma_f32_16x16x32_bf16(ap0, ldfrag(vbu, 32 + cl, g * 16), pva2, 0, 0, 0);
    pva2 = __builtin_amdgcn_mfma_f32_16x16x32_bf16(ap1, ldfrag(vbu, 32 + cl, 64 + g * 16), pva2, 0, 0, 0);
    pva3 = __builtin_amdgcn_mfma_f32_16x16x32_bf16(ap0, ldfrag(vbu, 48 + cl, g * 16), pva3, 0, 0, 0);
    pva3 = __builtin_amdgcn_mfma_f32_16x16x32_bf16(ap1, ldfrag(vbu, 48 + cl, 64 + g * 16), pva3, 0, 0, 0);
#pragma unroll
    for (int r = 0; r < 4; ++r)
      ab[(size_t)r * SEQ + vc * 64 + lane] = pval[r];
  }

  // output: lane stores dh-subtile j2 == g  => column = h*DH + lane
  u16* ob = o + (size_t)(b * SEQ + n0 + r0) * CH + h * DH + lane;
#pragma unroll
  for (int qq = 0; qq < 4; ++qq) {
    float v = pva0[qq];
    v = (g == 1) ? pva1[qq] : v;
    v = (g == 2) ? pva2[qq] : v;
    v = (g == 3) ? pva3[qq] : v;
    ob[(size_t)qq * CH] = f2bf(v);
  }
}

// ---------------------------------------------------------------------------
extern "C" void kernel_launch(void* const* d_in, const int* in_sizes, int n_in,
                              void* d_out, int out_size, void* d_ws, size_t ws_size,
                              hipStream_t stream)
{
  const float* x  = (const float*)d_in[0];
  const float* Wq = (const float*)d_in[1];
  const float* bq = (const float*)d_in[2];
  const float* Wk = (const float*)d_in[3];
  const float* bk = (const float*)d_in[4];
  const float* Wv = (const float*)d_in[5];
  const float* bv = (const float*)d_in[6];
  const float* Wo = (const float*)d_in[7];
  const float* bo = (const float*)d_in[8];

  float* out0 = (float*)d_out;                        // [B,SEQ,CH] fp32
  float* attn = out0 + (size_t)NBAT * SEQ * CH;       // [B,H,SEQ,SEQ] fp32

  const size_t T = (size_t)MTOT * CH;                 // 4M elems
  u16* xb  = (u16*)d_ws;
  u16* qw  = xb  + T;
  u16* kw  = qw  + T;
  u16* vtw = kw  + T;
  u16* ow  = vtw + T;
  u16* wtq = ow  + T;
  u16* wtk = wtq + (size_t)CH * CH;
  u16* wtv = wtk + (size_t)CH * CH;
  u16* wto = wtv + (size_t)CH * CH;

  cvt_x<<<T / (4 * 256), 256, 0, stream>>>(x, xb);
  wt_bf16<<<dim3(16, 16), 256, 0, stream>>>(Wq, wtq);
  wt_bf16<<<dim3(16, 16), 256, 0, stream>>>(Wk, wtk);
  wt_bf16<<<dim3(16, 16), 256, 0, stream>>>(Wv, wtv);
  wt_bf16<<<dim3(16, 16), 256, 0, stream>>>(Wo, wto);

  gemm_qkv<<<dim3(CH / 128, MTOT / 128, 3), 256, 0, stream>>>(
      xb, wtq, bq, qw, wtk, bk, kw, wtv, bv, vtw);

  fused_attn<<<4096, 256, 0, stream>>>(qw, kw, vtw, attn, ow);

  gemm_out<<<dim3(CH / 128, MTOT / 128), 256, 0, stream>>>(ow, wto, bo, out0);
}

// Round 11
// 270.285 us; speedup vs baseline: 3.3622x; 1.0681x over previous
//
#include <hip/hip_runtime.h>
#include <hip/hip_bf16.h>
#include <stdint.h>

#define NBAT 4
#define SEQ 1024
#define CH 1024
#define NH 16
#define DH 64
#define MTOT (NBAT*SEQ)   // 4096

typedef __attribute__((ext_vector_type(8))) short bf16x8;
typedef __attribute__((ext_vector_type(4))) float f32x4;
typedef unsigned short u16;

// Raw barrier is NOT a compiler fence: bracket it (R2 lesson).
#define FENCE() asm volatile("" ::: "memory")
#define BAR() do { FENCE(); __builtin_amdgcn_s_barrier(); FENCE(); } while (0)
#define WAIT_VM0() asm volatile("s_waitcnt vmcnt(0)" ::: "memory")
#define WAIT_VM2() asm volatile("s_waitcnt vmcnt(2)" ::: "memory")
#define WAIT_VM6() asm volatile("s_waitcnt vmcnt(6)" ::: "memory")
#define WAIT_LGKM0() asm volatile("s_waitcnt lgkmcnt(0)" ::: "memory")

__device__ __forceinline__ void g2l16(void* lds, const void* g) {
  __builtin_amdgcn_global_load_lds(
      (const __attribute__((address_space(1))) uint32_t*)g,
      (__attribute__((address_space(3))) uint32_t*)lds, 16, 0, 0);
}

__device__ __forceinline__ u16 f2bf(float f) {   // RNE float->bf16
  union { float f; uint32_t u; } v; v.f = f;
  uint32_t lsb = (v.u >> 16) & 1u;
  v.u += 0x7fffu + lsb;
  return (u16)(v.u >> 16);
}

// swizzled bf16x8 fragment read from a [rows][64 u16] LDS tile (128 B rows)
__device__ __forceinline__ bf16x8 ldfrag(const u16* base, int row, int koff) {
  return *(const bf16x8*)((const char*)base + row * 128 + (koff ^ ((row & 7) << 4)));
}

// ---------------------------------------------------------------------------
// x fp32 -> bf16 (4M elems)
// ---------------------------------------------------------------------------
__global__ __launch_bounds__(256) void cvt_x(const float* __restrict__ x,
                                             u16* __restrict__ xb) {
  int i = blockIdx.x * 256 + threadIdx.x;
  float4 v = ((const float4*)x)[i];
  ushort4 o;
  o.x = f2bf(v.x); o.y = f2bf(v.y); o.z = f2bf(v.z); o.w = f2bf(v.w);
  ((ushort4*)xb)[i] = o;
}

// ---------------------------------------------------------------------------
// W fp32 [1024][1024] -> Wt bf16 [n][k] (transposed), 64x64 tiles
// ---------------------------------------------------------------------------
__global__ __launch_bounds__(256) void wt_bf16(const float* __restrict__ W,
                                               u16* __restrict__ Wt) {
  __shared__ u16 tile[64][65];
  const int bi = blockIdx.x;      // n-tile
  const int bj = blockIdx.y;      // k-tile
  const int t = threadIdx.x;
  const int c4 = (t & 15) * 4, rr = t >> 4;
#pragma unroll
  for (int p = 0; p < 4; p++) {
    int r = p * 16 + rr;          // k within tile
    float4 v = *(const float4*)(W + (size_t)(bj * 64 + r) * CH + bi * 64 + c4);
    tile[r][c4 + 0] = f2bf(v.x); tile[r][c4 + 1] = f2bf(v.y);
    tile[r][c4 + 2] = f2bf(v.z); tile[r][c4 + 3] = f2bf(v.w);
  }
  __syncthreads();
  const int n = t >> 2, ks = (t & 3) * 16;
  u16 tmp[16];
#pragma unroll
  for (int i = 0; i < 16; i++) tmp[i] = tile[ks + i][n];
#pragma unroll
  for (int s = 0; s < 4; s++) {
    ushort4 o; o.x = tmp[4*s]; o.y = tmp[4*s+1]; o.z = tmp[4*s+2]; o.w = tmp[4*s+3];
    *(ushort4*)(Wt + (size_t)(bi * 64 + n) * CH + bj * 64 + ks + 4 * s) = o;
  }
}

// ---------------------------------------------------------------------------
// bf16 MFMA GEMM body: C[4096][1024] = A[4096][1024] @ Bt^T + bias
// MODE 0: bf16 out [M][N] (scaled); MODE 1: bf16 out transposed [N][M];
// MODE 2: fp32 out [M][N].
// ---------------------------------------------------------------------------
template<int MODE>
__device__ __forceinline__ void gemm_body(
    u16* As, u16* Bs,
    const u16* __restrict__ A, const u16* __restrict__ Bt,
    const float* __restrict__ bias, void* __restrict__ outp,
    float scale, int bn0, int bm0, int t)
{
  const int wid = t >> 6, lane = t & 63;
  const int wr = wid >> 1, wc = wid & 1;
  const int cl = lane & 15, g = lane >> 4;

  f32x4 acc[4][4] = {};
  const u16* ga = A  + (size_t)(bm0 + (t >> 2)) * CH + (t & 3) * 8;
  const u16* gb = Bt + (size_t)(bn0 + (t >> 2)) * CH + (t & 3) * 8;

  for (int k0 = 0; k0 < CH; k0 += 32) {
    g2l16(As + t * 8,        ga + k0);
    g2l16(As + 2048 + t * 8, ga + (size_t)64 * CH + k0);
    g2l16(Bs + t * 8,        gb + k0);
    g2l16(Bs + 2048 + t * 8, gb + (size_t)64 * CH + k0);
    __syncthreads();
    bf16x8 af[4], bfr[4];
#pragma unroll
    for (int f = 0; f < 4; f++) {
      af[f]  = *(const bf16x8*)(As + (wr * 64 + f * 16 + cl) * 32 + g * 8);
      bfr[f] = *(const bf16x8*)(Bs + (wc * 64 + f * 16 + cl) * 32 + g * 8);
    }
#pragma unroll
    for (int i = 0; i < 4; i++)
#pragma unroll
      for (int j = 0; j < 4; j++)
        acc[i][j] = __builtin_amdgcn_mfma_f32_16x16x32_bf16(af[i], bfr[j], acc[i][j], 0, 0, 0);
    __syncthreads();
  }

#pragma unroll
  for (int i = 0; i < 4; i++)
#pragma unroll
    for (int j = 0; j < 4; j++) {
      const int row0 = bm0 + wr * 64 + i * 16 + g * 4;
      const int col  = bn0 + wc * 64 + j * 16 + cl;
      const float bb = bias[col];
      f32x4 v = acc[i][j];
      if (MODE == 0) {
        u16* o = (u16*)outp;
#pragma unroll
        for (int q = 0; q < 4; q++) o[(size_t)(row0 + q) * CH + col] = f2bf((v[q] + bb) * scale);
      } else if (MODE == 1) {
        u16* o = (u16*)outp;
        ushort4 pk;
        pk.x = f2bf(v[0] + bb); pk.y = f2bf(v[1] + bb);
        pk.z = f2bf(v[2] + bb); pk.w = f2bf(v[3] + bb);
        *(ushort4*)(o + (size_t)col * MTOT + row0) = pk;
      } else {
        float* o = (float*)outp;
#pragma unroll
        for (int q = 0; q < 4; q++) o[(size_t)(row0 + q) * CH + col] = v[q] + bb;
      }
    }
}

// Q/K/V in one launch: grid.z selects target (3x blocks -> 3 blocks/CU MFMA overlap)
__global__ __launch_bounds__(256) void gemm_qkv(
    const u16* __restrict__ A,
    const u16* __restrict__ Wtq, const float* __restrict__ bq, u16* __restrict__ qo,
    const u16* __restrict__ Wtk, const float* __restrict__ bk, u16* __restrict__ ko,
    const u16* __restrict__ Wtv, const float* __restrict__ bv, u16* __restrict__ vo)
{
  __shared__ u16 As[128 * 32];
  __shared__ u16 Bs[128 * 32];
  const int t = threadIdx.x;
  const int bn0 = blockIdx.x * 128, bm0 = blockIdx.y * 128;
  if (blockIdx.z == 0)
    gemm_body<0>(As, Bs, A, Wtq, bq, qo, 0.0625f, bn0, bm0, t);   // pre-scaled Q
  else if (blockIdx.z == 1)
    gemm_body<0>(As, Bs, A, Wtk, bk, ko, 1.0f, bn0, bm0, t);
  else
    gemm_body<1>(As, Bs, A, Wtv, bv, vo, 1.0f, bn0, bm0, t);
}

__global__ __launch_bounds__(256) void gemm_out(
    const u16* __restrict__ A, const u16* __restrict__ Bt,
    const float* __restrict__ bias, float* __restrict__ outp)
{
  __shared__ u16 As[128 * 32];
  __shared__ u16 Bs[128 * 32];
  gemm_body<2>(As, Bs, A, Bt, bias, outp, 1.0f, blockIdx.x * 128, blockIdx.y * 128,
               threadIdx.x);
}

// ---------------------------------------------------------------------------
// Fused scores -> entmax(1.5, Newton) -> PV, barrier-minimal.
// EXACT R7 structure (passed 3x at absmax 0.00488): scalar xa[4][16], scalar
// Newton 7 iters.  Packed-f32x2 variant is BANNED (R8/R9/R10 all fail with it,
// value varies run-to-run => codegen-level corruption).  Single new knob vs
// R7: NON-TEMPORAL attn stores (256 MB zero-reuse stream was thrashing L2 at
// 5 blocks/CU: FETCH 99 MB vs 12.8 at occ-3).
// ---------------------------------------------------------------------------
__global__ __launch_bounds__(256, 5) void fused_attn(
    const u16* __restrict__ q, const u16* __restrict__ k,
    const u16* __restrict__ vt, float* __restrict__ attn,
    u16* __restrict__ o)
{
  __shared__ u16 buf[3][64 * 64];   // 24 KB staging (K chunks, then V^T chunks)
  __shared__ u16 pcb[4 * 256];      // 2 KB, per-wave P bounce (4 rows x 64)

  const int t = threadIdx.x;
  const int w = t >> 6, lane = t & 63;
  const int cl = lane & 15, g = lane >> 4;

  // XCD-clustered decode: lin%8 fixes bh%8 => per-XCD K/V set L2-resident
  const int lin = blockIdx.x;
  const int u = lin >> 3;
  const int n0 = (u & 63) * 16;
  const int bh = (lin & 7) | ((u >> 6) << 3);
  const int b = bh >> 4, h = bh & 15;
  const int r0 = w * 4;

  const u16* qb = q  + ((size_t)(b * SEQ + n0) * CH + h * DH);
  const u16* kb = k  + ((size_t)(b * SEQ) * CH + h * DH);
  const u16* vb = vt + ((size_t)(h * DH) * MTOT + b * SEQ);

  // Replicated Q A-fragments (rows r0..r0+3 repeated): row cl -> r0+(cl&3)
  const bf16x8 aq0 = *(const bf16x8*)(qb + (size_t)(r0 + (cl & 3)) * CH + g * 8);
  const bf16x8 aq1 = *(const bf16x8*)(qb + (size_t)(r0 + (cl & 3)) * CH + 32 + g * 8);

  // staging geometry: 256 thr x 16 B = 4 KB -> 2 g2l16 per 8 KB chunk
  const int srow = t >> 3;                                    // 0..31
  const int sbyte = ((t & 7) * 16) ^ ((srow & 7) << 4);       // inv-swz src
  const int scol = sbyte >> 1;                                // u16 units

  // prologue: stage K chunks 0,1
  g2l16(buf[0] + t * 8,        kb + (size_t)srow * CH + scol);
  g2l16(buf[0] + 2048 + t * 8, kb + (size_t)(srow + 32) * CH + scol);
  g2l16(buf[1] + t * 8,        kb + (size_t)(64 + srow) * CH + scol);
  g2l16(buf[1] + 2048 + t * 8, kb + (size_t)(64 + srow + 32) * CH + scol);

  float xa[4][16];

  // ---- scores: 16 chunks of 64 K-rows, 1 barrier/chunk, depth-2 prefetch ----
#pragma unroll
  for (int c = 0; c < 16; ++c) {
    WAIT_LGKM0();                        // my ds reads of prev buf complete
    if (c < 15) { WAIT_VM2(); } else { WAIT_VM0(); }
    BAR();                               // chunk c staged by ALL threads
    if (c + 2 < 16) {
      const u16* kc = kb + (size_t)(64 * (c + 2)) * CH;
      u16* d = buf[(c + 2) % 3];
      g2l16(d + t * 8,        kc + (size_t)srow * CH + scol);
      g2l16(d + 2048 + t * 8, kc + (size_t)(srow + 32) * CH + scol);
    }
    const u16* kc = buf[c % 3];
    f32x4 sc0 = {}, sc1 = {}, sc2 = {}, sc3 = {};
    sc0 = __builtin_amdgcn_mfma_f32_16x16x32_bf16(aq0, ldfrag(kc, cl,      g * 16), sc0, 0, 0, 0);
    sc0 = __builtin_amdgcn_mfma_f32_16x16x32_bf16(aq1, ldfrag(kc, cl,      64 + g * 16), sc0, 0, 0, 0);
    sc1 = __builtin_amdgcn_mfma_f32_16x16x32_bf16(aq0, ldfrag(kc, 16 + cl, g * 16), sc1, 0, 0, 0);
    sc1 = __builtin_amdgcn_mfma_f32_16x16x32_bf16(aq1, ldfrag(kc, 16 + cl, 64 + g * 16), sc1, 0, 0, 0);
    sc2 = __builtin_amdgcn_mfma_f32_16x16x32_bf16(aq0, ldfrag(kc, 32 + cl, g * 16), sc2, 0, 0, 0);
    sc2 = __builtin_amdgcn_mfma_f32_16x16x32_bf16(aq1, ldfrag(kc, 32 + cl, 64 + g * 16), sc2, 0, 0, 0);
    sc3 = __builtin_amdgcn_mfma_f32_16x16x32_bf16(aq0, ldfrag(kc, 48 + cl, g * 16), sc3, 0, 0, 0);
    sc3 = __builtin_amdgcn_mfma_f32_16x16x32_bf16(aq1, ldfrag(kc, 48 + cl, 64 + g * 16), sc3, 0, 0, 0);
#pragma unroll
    for (int qq = 0; qq < 4; ++qq) {     // keep subtile j == g
      float v = sc0[qq];
      v = (g == 1) ? sc1[qq] : v;
      v = (g == 2) ? sc2[qq] : v;
      v = (g == 3) ? sc3[qq] : v;
      xa[qq][c] = v;                     // Q pre-scaled: already *(1/8)*(a-1)
    }
  }

  // stage V chunks 0,1 (V^T rows = dh); latency hides under Newton
  g2l16(buf[1] + t * 8,        vb + (size_t)srow * MTOT + scol);
  g2l16(buf[1] + 2048 + t * 8, vb + (size_t)(srow + 32) * MTOT + scol);
  g2l16(buf[2] + t * 8,        vb + (size_t)srow * MTOT + 64 + scol);
  g2l16(buf[2] + 2048 + t * 8, vb + (size_t)(srow + 32) * MTOT + 64 + scol);

  // ---- entmax tau via Newton (alpha=1.5), SCALAR, 4 rows/wave ----
  float tau[4];
#pragma unroll
  for (int r = 0; r < 4; ++r) {
    float m = xa[r][0];
#pragma unroll
    for (int j = 1; j < 16; ++j) m = fmaxf(m, xa[r][j]);
#pragma unroll
    for (int off = 1; off < 64; off <<= 1) m = fmaxf(m, __shfl_xor(m, off));
    tau[r] = m - 1.0f;
  }
  for (int it = 0; it < 7; ++it) {       // 7 iters: verified converged (R7)
    float ss[4], sd[4];
#pragma unroll
    for (int r = 0; r < 4; ++r) {
      float s2 = 0.f, s1 = 0.f;
#pragma unroll
      for (int j = 0; j < 16; ++j) {
        float d = fmaxf(xa[r][j] - tau[r], 0.f);
        s2 = fmaf(d, d, s2); s1 += d;
      }
      ss[r] = s2; sd[r] = s1;
    }
#pragma unroll
    for (int off = 1; off < 64; off <<= 1) {
#pragma unroll
      for (int r = 0; r < 4; ++r) {
        ss[r] += __shfl_xor(ss[r], off);
        sd[r] += __shfl_xor(sd[r], off);
      }
    }
#pragma unroll
    for (int r = 0; r < 4; ++r)
      tau[r] += (ss[r] - 1.0f) / (sd[r] + sd[r]);
  }
  float inv[4];
#pragma unroll
  for (int r = 0; r < 4; ++r) {
    float s2 = 0.f;
#pragma unroll
    for (int j = 0; j < 16; ++j) { float d = fmaxf(xa[r][j] - tau[r], 0.f); s2 = fmaf(d, d, s2); }
#pragma unroll
    for (int off = 1; off < 64; off <<= 1) s2 += __shfl_xor(s2, off);
    inv[r] = 1.0f / s2;
  }

  // ---- PV: 16 chunks of 64 V-rows, 1 barrier/chunk ----
  char* pw = (char*)pcb + w * 512;       // wave-private P bounce
  f32x4 pva0 = {}, pva1 = {}, pva2 = {}, pva3 = {};
  float* ab = attn + (size_t)bh * SEQ * SEQ + (size_t)(n0 + r0) * SEQ;
#pragma unroll
  for (int vc = 0; vc < 16; ++vc) {
    float pval[4];
#pragma unroll
    for (int r = 0; r < 4; ++r) {
      float d = fmaxf(xa[r][vc] - tau[r], 0.f);
      pval[r] = d * d * inv[r];
      *(u16*)(pw + r * 128 + ((lane * 2) ^ (r << 4))) = f2bf(pval[r]);
    }
    WAIT_LGKM0();                        // pcb writes + prev frag reads done
    if (vc == 0) { WAIT_VM2(); } else { WAIT_VM6(); }
    BAR();                               // V chunk vc staged for all threads
    if (vc + 2 < 16) {
      const u16* vc2 = vb + (size_t)64 * (vc + 2);
      u16* d = buf[(16 + vc + 2) % 3];
      g2l16(d + t * 8,        vc2 + (size_t)srow * MTOT + scol);
      g2l16(d + 2048 + t * 8, vc2 + (size_t)(srow + 32) * MTOT + scol);
    }
    const u16* vbu = buf[(16 + vc) % 3];
    const bf16x8 ap0 = *(const bf16x8*)(pw + (cl & 3) * 128 + ((g * 16) ^ ((cl & 3) << 4)));
    const bf16x8 ap1 = *(const bf16x8*)(pw + (cl & 3) * 128 + ((64 + g * 16) ^ ((cl & 3) << 4)));
    pva0 = __builtin_amdgcn_mfma_f32_16x16x32_bf16(ap0, ldfrag(vbu, cl,      g * 16), pva0, 0, 0, 0);
    pva0 = __builtin_amdgcn_mfma_f32_16x16x32_bf16(ap1, ldfrag(vbu, cl,      64 + g * 16), pva0, 0, 0, 0);
    pva1 = __builtin_amdgcn_mfma_f32_16x16x32_bf16(ap0, ldfrag(vbu, 16 + cl, g * 16), pva1, 0, 0, 0);
    pva1 = __builtin_amdgcn_mfma_f32_16x16x32_bf16(ap1, ldfrag(vbu, 16 + cl, 64 + g * 16), pva1, 0, 0, 0);
    pva2 = __builtin_amdgcn_mfma_f32_16x16x32_bf16(ap0, ldfrag(vbu, 32 + cl, g * 16), pva2, 0, 0, 0);
    pva2 = __builtin_amdgcn_mfma_f32_16x16x32_bf16(ap1, ldfrag(vbu, 32 + cl, 64 + g * 16), pva2, 0, 0, 0);
    pva3 = __builtin_amdgcn_mfma_f32_16x16x32_bf16(ap0, ldfrag(vbu, 48 + cl, g * 16), pva3, 0, 0, 0);
    pva3 = __builtin_amdgcn_mfma_f32_16x16x32_bf16(ap1, ldfrag(vbu, 48 + cl, 64 + g * 16), pva3, 0, 0, 0);
#pragma unroll
    for (int r = 0; r < 4; ++r)
      __builtin_nontemporal_store(pval[r], ab + (size_t)r * SEQ + vc * 64 + lane);
  }

  // output: lane stores dh-subtile j2 == g  => column = h*DH + lane
  u16* ob = o + (size_t)(b * SEQ + n0 + r0) * CH + h * DH + lane;
#pragma unroll
  for (int qq = 0; qq < 4; ++qq) {
    float v = pva0[qq];
    v = (g == 1) ? pva1[qq] : v;
    v = (g == 2) ? pva2[qq] : v;
    v = (g == 3) ? pva3[qq] : v;
    ob[(size_t)qq * CH] = f2bf(v);
  }
}

// ---------------------------------------------------------------------------
extern "C" void kernel_launch(void* const* d_in, const int* in_sizes, int n_in,
                              void* d_out, int out_size, void* d_ws, size_t ws_size,
                              hipStream_t stream)
{
  const float* x  = (const float*)d_in[0];
  const float* Wq = (const float*)d_in[1];
  const float* bq = (const float*)d_in[2];
  const float* Wk = (const float*)d_in[3];
  const float* bk = (const float*)d_in[4];
  const float* Wv = (const float*)d_in[5];
  const float* bv = (const float*)d_in[6];
  const float* Wo = (const float*)d_in[7];
  const float* bo = (const float*)d_in[8];

  float* out0 = (float*)d_out;                        // [B,SEQ,CH] fp32
  float* attn = out0 + (size_t)NBAT * SEQ * CH;       // [B,H,SEQ,SEQ] fp32

  const size_t T = (size_t)MTOT * CH;                 // 4M elems
  u16* xb  = (u16*)d_ws;
  u16* qw  = xb  + T;
  u16* kw  = qw  + T;
  u16* vtw = kw  + T;
  u16* ow  = vtw + T;
  u16* wtq = ow  + T;
  u16* wtk = wtq + (size_t)CH * CH;
  u16* wtv = wtk + (size_t)CH * CH;
  u16* wto = wtv + (size_t)CH * CH;

  cvt_x<<<T / (4 * 256), 256, 0, stream>>>(x, xb);
  wt_bf16<<<dim3(16, 16), 256, 0, stream>>>(Wq, wtq);
  wt_bf16<<<dim3(16, 16), 256, 0, stream>>>(Wk, wtk);
  wt_bf16<<<dim3(16, 16), 256, 0, stream>>>(Wv, wtv);
  wt_bf16<<<dim3(16, 16), 256, 0, stream>>>(Wo, wto);

  gemm_qkv<<<dim3(CH / 128, MTOT / 128, 3), 256, 0, stream>>>(
      xb, wtq, bq, qw, wtk, bk, kw, wtv, bv, vtw);

  fused_attn<<<4096, 256, 0, stream>>>(qw, kw, vtw, attn, ow);

  gemm_out<<<dim3(CH / 128, MTOT / 128), 256, 0, stream>>>(ow, wto, bo, out0);
}

// Round 12
// 245.313 us; speedup vs baseline: 3.7045x; 1.1018x over previous
//
#include <hip/hip_runtime.h>
#include <hip/hip_bf16.h>
#include <stdint.h>

#define NBAT 4
#define SEQ 1024
#define CH 1024
#define NH 16
#define DH 64
#define MTOT (NBAT*SEQ)   // 4096

typedef __attribute__((ext_vector_type(8))) short bf16x8;
typedef __attribute__((ext_vector_type(4))) float f32x4;
typedef unsigned short u16;

// Raw barrier is NOT a compiler fence: bracket it (R2 lesson).
#define FENCE() asm volatile("" ::: "memory")
#define BAR() do { FENCE(); __builtin_amdgcn_s_barrier(); FENCE(); } while (0)
#define WAIT_VM0() asm volatile("s_waitcnt vmcnt(0)" ::: "memory")
#define WAIT_VM8() asm volatile("s_waitcnt vmcnt(8)" ::: "memory")
#define WAIT_LGKM0() asm volatile("s_waitcnt lgkmcnt(0)" ::: "memory")

__device__ __forceinline__ void g2l16(void* lds, const void* g) {
  __builtin_amdgcn_global_load_lds(
      (const __attribute__((address_space(1))) uint32_t*)g,
      (__attribute__((address_space(3))) uint32_t*)lds, 16, 0, 0);
}

__device__ __forceinline__ u16 f2bf(float f) {   // RNE float->bf16
  union { float f; uint32_t u; } v; v.f = f;
  uint32_t lsb = (v.u >> 16) & 1u;
  v.u += 0x7fffu + lsb;
  return (u16)(v.u >> 16);
}

// swizzled bf16x8 fragment read from a [rows][64 u16] LDS tile (128 B rows)
__device__ __forceinline__ bf16x8 ldfrag(const u16* base, int row, int koff) {
  return *(const bf16x8*)((const char*)base + row * 128 + (koff ^ ((row & 7) << 4)));
}

// ---------------------------------------------------------------------------
// x fp32 -> bf16 (4M elems)
// ---------------------------------------------------------------------------
__global__ __launch_bounds__(256) void cvt_x(const float* __restrict__ x,
                                             u16* __restrict__ xb) {
  int i = blockIdx.x * 256 + threadIdx.x;
  float4 v = ((const float4*)x)[i];
  ushort4 o;
  o.x = f2bf(v.x); o.y = f2bf(v.y); o.z = f2bf(v.z); o.w = f2bf(v.w);
  ((ushort4*)xb)[i] = o;
}

// ---------------------------------------------------------------------------
// W fp32 [1024][1024] -> Wt bf16 [n][k] (transposed), 64x64 tiles
// ---------------------------------------------------------------------------
__global__ __launch_bounds__(256) void wt_bf16(const float* __restrict__ W,
                                               u16* __restrict__ Wt) {
  __shared__ u16 tile[64][65];
  const int bi = blockIdx.x;      // n-tile
  const int bj = blockIdx.y;      // k-tile
  const int t = threadIdx.x;
  const int c4 = (t & 15) * 4, rr = t >> 4;
#pragma unroll
  for (int p = 0; p < 4; p++) {
    int r = p * 16 + rr;          // k within tile
    float4 v = *(const float4*)(W + (size_t)(bj * 64 + r) * CH + bi * 64 + c4);
    tile[r][c4 + 0] = f2bf(v.x); tile[r][c4 + 1] = f2bf(v.y);
    tile[r][c4 + 2] = f2bf(v.z); tile[r][c4 + 3] = f2bf(v.w);
  }
  __syncthreads();
  const int n = t >> 2, ks = (t & 3) * 16;
  u16 tmp[16];
#pragma unroll
  for (int i = 0; i < 16; i++) tmp[i] = tile[ks + i][n];
#pragma unroll
  for (int s = 0; s < 4; s++) {
    ushort4 o; o.x = tmp[4*s]; o.y = tmp[4*s+1]; o.z = tmp[4*s+2]; o.w = tmp[4*s+3];
    *(ushort4*)(Wt + (size_t)(bi * 64 + n) * CH + bj * 64 + ks + 4 * s) = o;
  }
}

// ---------------------------------------------------------------------------
// bf16 MFMA GEMM body: C[4096][1024] = A[4096][1024] @ Bt^T + bias
// ---------------------------------------------------------------------------
template<int MODE>
__device__ __forceinline__ void gemm_body(
    u16* As, u16* Bs,
    const u16* __restrict__ A, const u16* __restrict__ Bt,
    const float* __restrict__ bias, void* __restrict__ outp,
    float scale, int bn0, int bm0, int t)
{
  const int wid = t >> 6, lane = t & 63;
  const int wr = wid >> 1, wc = wid & 1;
  const int cl = lane & 15, g = lane >> 4;

  f32x4 acc[4][4] = {};
  const u16* ga = A  + (size_t)(bm0 + (t >> 2)) * CH + (t & 3) * 8;
  const u16* gb = Bt + (size_t)(bn0 + (t >> 2)) * CH + (t & 3) * 8;

  for (int k0 = 0; k0 < CH; k0 += 32) {
    g2l16(As + t * 8,        ga + k0);
    g2l16(As + 2048 + t * 8, ga + (size_t)64 * CH + k0);
    g2l16(Bs + t * 8,        gb + k0);
    g2l16(Bs + 2048 + t * 8, gb + (size_t)64 * CH + k0);
    __syncthreads();
    bf16x8 af[4], bfr[4];
#pragma unroll
    for (int f = 0; f < 4; f++) {
      af[f]  = *(const bf16x8*)(As + (wr * 64 + f * 16 + cl) * 32 + g * 8);
      bfr[f] = *(const bf16x8*)(Bs + (wc * 64 + f * 16 + cl) * 32 + g * 8);
    }
#pragma unroll
    for (int i = 0; i < 4; i++)
#pragma unroll
      for (int j = 0; j < 4; j++)
        acc[i][j] = __builtin_amdgcn_mfma_f32_16x16x32_bf16(af[i], bfr[j], acc[i][j], 0, 0, 0);
    __syncthreads();
  }

#pragma unroll
  for (int i = 0; i < 4; i++)
#pragma unroll
    for (int j = 0; j < 4; j++) {
      const int row0 = bm0 + wr * 64 + i * 16 + g * 4;
      const int col  = bn0 + wc * 64 + j * 16 + cl;
      const float bb = bias[col];
      f32x4 v = acc[i][j];
      if (MODE == 0) {
        u16* o = (u16*)outp;
#pragma unroll
        for (int q = 0; q < 4; q++) o[(size_t)(row0 + q) * CH + col] = f2bf((v[q] + bb) * scale);
      } else if (MODE == 1) {
        u16* o = (u16*)outp;
        ushort4 pk;
        pk.x = f2bf(v[0] + bb); pk.y = f2bf(v[1] + bb);
        pk.z = f2bf(v[2] + bb); pk.w = f2bf(v[3] + bb);
        *(ushort4*)(o + (size_t)col * MTOT + row0) = pk;
      } else {
        float* o = (float*)outp;
#pragma unroll
        for (int q = 0; q < 4; q++) o[(size_t)(row0 + q) * CH + col] = v[q] + bb;
      }
    }
}

// Q/K/V in one launch: grid.z selects target
__global__ __launch_bounds__(256) void gemm_qkv(
    const u16* __restrict__ A,
    const u16* __restrict__ Wtq, const float* __restrict__ bq, u16* __restrict__ qo,
    const u16* __restrict__ Wtk, const float* __restrict__ bk, u16* __restrict__ ko,
    const u16* __restrict__ Wtv, const float* __restrict__ bv, u16* __restrict__ vo)
{
  __shared__ u16 As[128 * 32];
  __shared__ u16 Bs[128 * 32];
  const int t = threadIdx.x;
  const int bn0 = blockIdx.x * 128, bm0 = blockIdx.y * 128;
  if (blockIdx.z == 0)
    gemm_body<0>(As, Bs, A, Wtq, bq, qo, 0.0625f, bn0, bm0, t);   // pre-scaled Q
  else if (blockIdx.z == 1)
    gemm_body<0>(As, Bs, A, Wtk, bk, ko, 1.0f, bn0, bm0, t);
  else
    gemm_body<1>(As, Bs, A, Wtv, bv, vo, 1.0f, bn0, bm0, t);
}

__global__ __launch_bounds__(256) void gemm_out(
    const u16* __restrict__ A, const u16* __restrict__ Bt,
    const float* __restrict__ bias, float* __restrict__ outp)
{
  __shared__ u16 As[128 * 32];
  __shared__ u16 Bs[128 * 32];
  gemm_body<2>(As, Bs, A, Bt, bias, outp, 1.0f, blockIdx.x * 128, blockIdx.y * 128,
               threadIdx.x);
}

// ---------------------------------------------------------------------------
// Fused scores -> entmax(1.5, Newton) -> PV.
// R12: 128-row chunks (8 score + 8 PV iters; HALF the barriers of R11).
// Chunk = two 8 KB sub-tiles (64 rows x 128 B, XOR-swizzled), double-buffered
// 16 KB buffers (LDS 36 KB -> 4 blocks/CU).  Depth-1 prefetch; waits by queue
// simulation: scores vmcnt(0) [outstanding == this chunk's 4 staging ops],
// PV vmcnt(8) [prev iter's 8 attn stores float across the barrier].
// Scalar xa[4][16], scalar Newton 7 iters (verified).  NT attn stores.
// ---------------------------------------------------------------------------
__global__ __launch_bounds__(256, 4) void fused_attn(
    const u16* __restrict__ q, const u16* __restrict__ k,
    const u16* __restrict__ vt, float* __restrict__ attn,
    u16* __restrict__ o)
{
  __shared__ u16 buf[2][128 * 64];   // 2 x 16 KB (each: two 64x64 sub-tiles)
  __shared__ u16 pcb[2][4 * 256];    // 2 x 2 KB, per-sub per-wave P bounce

  const int t = threadIdx.x;
  const int w = t >> 6, lane = t & 63;
  const int cl = lane & 15, g = lane >> 4;

  // XCD-clustered decode: lin%8 fixes bh%8 => per-XCD K/V set L2-resident
  const int lin = blockIdx.x;
  const int u = lin >> 3;
  const int n0 = (u & 63) * 16;
  const int bh = (lin & 7) | ((u >> 6) << 3);
  const int b = bh >> 4, h = bh & 15;
  const int r0 = w * 4;

  const u16* qb = q  + ((size_t)(b * SEQ + n0) * CH + h * DH);
  const u16* kb = k  + ((size_t)(b * SEQ) * CH + h * DH);
  const u16* vb = vt + ((size_t)(h * DH) * MTOT + b * SEQ);

  // Replicated Q A-fragments (rows r0..r0+3 repeated): row cl -> r0+(cl&3)
  const bf16x8 aq0 = *(const bf16x8*)(qb + (size_t)(r0 + (cl & 3)) * CH + g * 8);
  const bf16x8 aq1 = *(const bf16x8*)(qb + (size_t)(r0 + (cl & 3)) * CH + 32 + g * 8);

  // staging geometry: 256 thr x 16 B = 4 KB per call -> 4 calls per 16 KB chunk
  const int srow = t >> 3;                                    // 0..31
  const int sbyte = ((t & 7) * 16) ^ ((srow & 7) << 4);       // inv-swz src
  const int scol = sbyte >> 1;                                // u16 units

  // prologue: stage K chunk 0 (rows 0..127)
  {
    u16* d = buf[0];
    g2l16(d + t * 8,        kb + (size_t)srow * CH + scol);
    g2l16(d + 2048 + t * 8, kb + (size_t)(srow + 32) * CH + scol);
    g2l16(d + 4096 + t * 8, kb + (size_t)(srow + 64) * CH + scol);
    g2l16(d + 6144 + t * 8, kb + (size_t)(srow + 96) * CH + scol);
  }

  float xa[4][16];

  // ---- scores: 8 chunks of 128 K-rows ----
#pragma unroll
  for (int c = 0; c < 8; ++c) {
    WAIT_LGKM0();                        // my ds reads of other buf complete
    WAIT_VM0();                          // chunk c staging (exactly 4 ops) done
    BAR();
    if (c < 7) {
      const u16* kc = kb + (size_t)(128 * (c + 1)) * CH;
      u16* d = buf[(c + 1) & 1];
      g2l16(d + t * 8,        kc + (size_t)srow * CH + scol);
      g2l16(d + 2048 + t * 8, kc + (size_t)(srow + 32) * CH + scol);
      g2l16(d + 4096 + t * 8, kc + (size_t)(srow + 64) * CH + scol);
      g2l16(d + 6144 + t * 8, kc + (size_t)(srow + 96) * CH + scol);
    }
#pragma unroll
    for (int s = 0; s < 2; ++s) {        // two 64-row sub-tiles
      const u16* kc = buf[c & 1] + s * 4096;
      f32x4 sc0 = {}, sc1 = {}, sc2 = {}, sc3 = {};
      sc0 = __builtin_amdgcn_mfma_f32_16x16x32_bf16(aq0, ldfrag(kc, cl,      g * 16), sc0, 0, 0, 0);
      sc0 = __builtin_amdgcn_mfma_f32_16x16x32_bf16(aq1, ldfrag(kc, cl,      64 + g * 16), sc0, 0, 0, 0);
      sc1 = __builtin_amdgcn_mfma_f32_16x16x32_bf16(aq0, ldfrag(kc, 16 + cl, g * 16), sc1, 0, 0, 0);
      sc1 = __builtin_amdgcn_mfma_f32_16x16x32_bf16(aq1, ldfrag(kc, 16 + cl, 64 + g * 16), sc1, 0, 0, 0);
      sc2 = __builtin_amdgcn_mfma_f32_16x16x32_bf16(aq0, ldfrag(kc, 32 + cl, g * 16), sc2, 0, 0, 0);
      sc2 = __builtin_amdgcn_mfma_f32_16x16x32_bf16(aq1, ldfrag(kc, 32 + cl, 64 + g * 16), sc2, 0, 0, 0);
      sc3 = __builtin_amdgcn_mfma_f32_16x16x32_bf16(aq0, ldfrag(kc, 48 + cl, g * 16), sc3, 0, 0, 0);
      sc3 = __builtin_amdgcn_mfma_f32_16x16x32_bf16(aq1, ldfrag(kc, 48 + cl, 64 + g * 16), sc3, 0, 0, 0);
#pragma unroll
      for (int qq = 0; qq < 4; ++qq) {   // keep row-tile == g
        float v = sc0[qq];
        v = (g == 1) ? sc1[qq] : v;
        v = (g == 2) ? sc2[qq] : v;
        v = (g == 3) ? sc3[qq] : v;
        xa[qq][2 * c + s] = v;           // Q pre-scaled: already *(1/8)*(a-1)
      }
    }
  }

  // stage V chunk 0 (V^T: 64 dh rows x m 0..127); latency hides under Newton
  {
    u16* d = buf[0];
    g2l16(d + t * 8,        vb + (size_t)srow * MTOT + scol);
    g2l16(d + 2048 + t * 8, vb + (size_t)(srow + 32) * MTOT + scol);
    g2l16(d + 4096 + t * 8, vb + (size_t)srow * MTOT + 64 + scol);
    g2l16(d + 6144 + t * 8, vb + (size_t)(srow + 32) * MTOT + 64 + scol);
  }

  // ---- entmax tau via Newton (alpha=1.5), SCALAR, 4 rows/wave ----
  float tau[4];
#pragma unroll
  for (int r = 0; r < 4; ++r) {
    float m = xa[r][0];
#pragma unroll
    for (int j = 1; j < 16; ++j) m = fmaxf(m, xa[r][j]);
#pragma unroll
    for (int off = 1; off < 64; off <<= 1) m = fmaxf(m, __shfl_xor(m, off));
    tau[r] = m - 1.0f;
  }
  for (int it = 0; it < 7; ++it) {       // 7 iters: verified converged (R7/R11)
    float ss[4], sd[4];
#pragma unroll
    for (int r = 0; r < 4; ++r) {
      float s2 = 0.f, s1 = 0.f;
#pragma unroll
      for (int j = 0; j < 16; ++j) {
        float d = fmaxf(xa[r][j] - tau[r], 0.f);
        s2 = fmaf(d, d, s2); s1 += d;
      }
      ss[r] = s2; sd[r] = s1;
    }
#pragma unroll
    for (int off = 1; off < 64; off <<= 1) {
#pragma unroll
      for (int r = 0; r < 4; ++r) {
        ss[r] += __shfl_xor(ss[r], off);
        sd[r] += __shfl_xor(sd[r], off);
      }
    }
#pragma unroll
    for (int r = 0; r < 4; ++r)
      tau[r] += (ss[r] - 1.0f) / (sd[r] + sd[r]);
  }
  float inv[4];
#pragma unroll
  for (int r = 0; r < 4; ++r) {
    float s2 = 0.f;
#pragma unroll
    for (int j = 0; j < 16; ++j) { float d = fmaxf(xa[r][j] - tau[r], 0.f); s2 = fmaf(d, d, s2); }
#pragma unroll
    for (int off = 1; off < 64; off <<= 1) s2 += __shfl_xor(s2, off);
    inv[r] = 1.0f / s2;
  }

  // ---- PV: 8 chunks of 128 V-rows ----
  f32x4 pva0 = {}, pva1 = {}, pva2 = {}, pva3 = {};
  float* ab = attn + (size_t)bh * SEQ * SEQ + (size_t)(n0 + r0) * SEQ;
#pragma unroll
  for (int vc = 0; vc < 8; ++vc) {
    float pval[2][4];
#pragma unroll
    for (int s = 0; s < 2; ++s) {
      char* pw = (char*)pcb[s] + w * 512;
#pragma unroll
      for (int r = 0; r < 4; ++r) {
        float d = fmaxf(xa[r][2 * vc + s] - tau[r], 0.f);
        pval[s][r] = d * d * inv[r];
        *(u16*)(pw + r * 128 + ((lane * 2) ^ (r << 4))) = f2bf(pval[s][r]);
      }
    }
    WAIT_LGKM0();                        // pcb writes + prev ds reads done
    if (vc == 0) { WAIT_VM0(); } else { WAIT_VM8(); }  // pf(vc) done; prev stores float
    BAR();
    if (vc < 7) {
      const u16* vc2 = vb + (size_t)128 * (vc + 1);
      u16* d = buf[(vc + 1) & 1];
      g2l16(d + t * 8,        vc2 + (size_t)srow * MTOT + scol);
      g2l16(d + 2048 + t * 8, vc2 + (size_t)(srow + 32) * MTOT + scol);
      g2l16(d + 4096 + t * 8, vc2 + (size_t)srow * MTOT + 64 + scol);
      g2l16(d + 6144 + t * 8, vc2 + (size_t)(srow + 32) * MTOT + 64 + scol);
    }
#pragma unroll
    for (int s = 0; s < 2; ++s) {
      const u16* vbu = buf[vc & 1] + s * 4096;
      const char* pw = (const char*)pcb[s] + w * 512;
      const bf16x8 ap0 = *(const bf16x8*)(pw + (cl & 3) * 128 + ((g * 16) ^ ((cl & 3) << 4)));
      const bf16x8 ap1 = *(const bf16x8*)(pw + (cl & 3) * 128 + ((64 + g * 16) ^ ((cl & 3) << 4)));
      pva0 = __builtin_amdgcn_mfma_f32_16x16x32_bf16(ap0, ldfrag(vbu, cl,      g * 16), pva0, 0, 0, 0);
      pva0 = __builtin_amdgcn_mfma_f32_16x16x32_bf16(ap1, ldfrag(vbu, cl,      64 + g * 16), pva0, 0, 0, 0);
      pva1 = __builtin_amdgcn_mfma_f32_16x16x32_bf16(ap0, ldfrag(vbu, 16 + cl, g * 16), pva1, 0, 0, 0);
      pva1 = __builtin_amdgcn_mfma_f32_16x16x32_bf16(ap1, ldfrag(vbu, 16 + cl, 64 + g * 16), pva1, 0, 0, 0);
      pva2 = __builtin_amdgcn_mfma_f32_16x16x32_bf16(ap0, ldfrag(vbu, 32 + cl, g * 16), pva2, 0, 0, 0);
      pva2 = __builtin_amdgcn_mfma_f32_16x16x32_bf16(ap1, ldfrag(vbu, 32 + cl, 64 + g * 16), pva2, 0, 0, 0);
      pva3 = __builtin_amdgcn_mfma_f32_16x16x32_bf16(ap0, ldfrag(vbu, 48 + cl, g * 16), pva3, 0, 0, 0);
      pva3 = __builtin_amdgcn_mfma_f32_16x16x32_bf16(ap1, ldfrag(vbu, 48 + cl, 64 + g * 16), pva3, 0, 0, 0);
    }
#pragma unroll
    for (int s = 0; s < 2; ++s)
#pragma unroll
      for (int r = 0; r < 4; ++r)
        __builtin_nontemporal_store(pval[s][r],
            ab + (size_t)r * SEQ + (2 * vc + s) * 64 + lane);
  }

  // output: lane stores dh-subtile == g  => column = h*DH + lane
  u16* ob = o + (size_t)(b * SEQ + n0 + r0) * CH + h * DH + lane;
#pragma unroll
  for (int qq = 0; qq < 4; ++qq) {
    float v = pva0[qq];
    v = (g == 1) ? pva1[qq] : v;
    v = (g == 2) ? pva2[qq] : v;
    v = (g == 3) ? pva3[qq] : v;
    ob[(size_t)qq * CH] = f2bf(v);
  }
}

// ---------------------------------------------------------------------------
extern "C" void kernel_launch(void* const* d_in, const int* in_sizes, int n_in,
                              void* d_out, int out_size, void* d_ws, size_t ws_size,
                              hipStream_t stream)
{
  const float* x  = (const float*)d_in[0];
  const float* Wq = (const float*)d_in[1];
  const float* bq = (const float*)d_in[2];
  const float* Wk = (const float*)d_in[3];
  const float* bk = (const float*)d_in[4];
  const float* Wv = (const float*)d_in[5];
  const float* bv = (const float*)d_in[6];
  const float* Wo = (const float*)d_in[7];
  const float* bo = (const float*)d_in[8];

  float* out0 = (float*)d_out;                        // [B,SEQ,CH] fp32
  float* attn = out0 + (size_t)NBAT * SEQ * CH;       // [B,H,SEQ,SEQ] fp32

  const size_t T = (size_t)MTOT * CH;                 // 4M elems
  u16* xb  = (u16*)d_ws;
  u16* qw  = xb  + T;
  u16* kw  = qw  + T;
  u16* vtw = kw  + T;
  u16* ow  = vtw + T;
  u16* wtq = ow  + T;
  u16* wtk = wtq + (size_t)CH * CH;
  u16* wtv = wtk + (size_t)CH * CH;
  u16* wto = wtv + (size_t)CH * CH;

  cvt_x<<<T / (4 * 256), 256, 0, stream>>>(x, xb);
  wt_bf16<<<dim3(16, 16), 256, 0, stream>>>(Wq, wtq);
  wt_bf16<<<dim3(16, 16), 256, 0, stream>>>(Wk, wtk);
  wt_bf16<<<dim3(16, 16), 256, 0, stream>>>(Wv, wtv);
  wt_bf16<<<dim3(16, 16), 256, 0, stream>>>(Wo, wto);

  gemm_qkv<<<dim3(CH / 128, MTOT / 128, 3), 256, 0, stream>>>(
      xb, wtq, bq, qw, wtk, bk, kw, wtv, bv, vtw);

  fused_attn<<<4096, 256, 0, stream>>>(qw, kw, vtw, attn, ow);

  gemm_out<<<dim3(CH / 128, MTOT / 128), 256, 0, stream>>>(ow, wto, bo, out0);
}